// Round 9
// baseline (775.015 us; speedup 1.0000x reference)
//
#include <hip/hip_runtime.h>

#define AS1 __attribute__((address_space(1)))
#define AS3 __attribute__((address_space(3)))

typedef __bf16 bf16x8 __attribute__((ext_vector_type(8)));
typedef float f32x4 __attribute__((ext_vector_type(4)));

// ---------- small helpers ----------
__device__ __forceinline__ unsigned short f2bf(float f) {
  unsigned u = __float_as_uint(f);
  u += 0x7FFFu + ((u >> 16) & 1u);   // RNE
  return (unsigned short)(u >> 16);
}
__device__ __forceinline__ float bf2f(unsigned short u) {
  return __uint_as_float(((unsigned)u) << 16);
}

__device__ __forceinline__ void gl_lds16(const void* g, void* l) {
  // async global->LDS, 16B per lane; LDS dest = wave-uniform base + lane*16
  __builtin_amdgcn_global_load_lds((const AS1 unsigned int*)g,
                                   (AS3 unsigned int*)l, 16, 0, 0);
}

// ---------- Threefry-2x32 (20 rounds), JAX-compatible ----------
__device__ __forceinline__ unsigned rotl32(unsigned v, int s) {
  return (v << s) | (v >> (32 - s));
}
__device__ __forceinline__ void threefry2x32(unsigned k0, unsigned k1,
                                             unsigned x0, unsigned x1,
                                             unsigned& o0, unsigned& o1) {
  const unsigned ks2 = k0 ^ k1 ^ 0x1BD11BDAu;
  x0 += k0; x1 += k1;
  x0 += x1; x1 = rotl32(x1, 13); x1 ^= x0;
  x0 += x1; x1 = rotl32(x1, 15); x1 ^= x0;
  x0 += x1; x1 = rotl32(x1, 26); x1 ^= x0;
  x0 += x1; x1 = rotl32(x1, 6);  x1 ^= x0;
  x0 += k1; x1 += ks2 + 1u;
  x0 += x1; x1 = rotl32(x1, 17); x1 ^= x0;
  x0 += x1; x1 = rotl32(x1, 29); x1 ^= x0;
  x0 += x1; x1 = rotl32(x1, 16); x1 ^= x0;
  x0 += x1; x1 = rotl32(x1, 24); x1 ^= x0;
  x0 += ks2; x1 += k0 + 2u;
  x0 += x1; x1 = rotl32(x1, 13); x1 ^= x0;
  x0 += x1; x1 = rotl32(x1, 15); x1 ^= x0;
  x0 += x1; x1 = rotl32(x1, 26); x1 ^= x0;
  x0 += x1; x1 = rotl32(x1, 6);  x1 ^= x0;
  x0 += k0; x1 += k1 + 3u;
  x0 += x1; x1 = rotl32(x1, 17); x1 ^= x0;
  x0 += x1; x1 = rotl32(x1, 29); x1 ^= x0;
  x0 += x1; x1 = rotl32(x1, 16); x1 ^= x0;
  x0 += x1; x1 = rotl32(x1, 24); x1 ^= x0;
  x0 += k1; x1 += ks2 + 4u;
  x0 += x1; x1 = rotl32(x1, 13); x1 ^= x0;
  x0 += x1; x1 = rotl32(x1, 15); x1 ^= x0;
  x0 += x1; x1 = rotl32(x1, 26); x1 ^= x0;
  x0 += x1; x1 = rotl32(x1, 6);  x1 ^= x0;
  o0 = x0 + ks2; o1 = x1 + k0 + 5u;
}

// XLA f32 erf_inv (Giles polynomial)
__device__ __forceinline__ float erfinv32(float x) {
  float w = -log1pf(-x * x);
  float p;
  if (w < 5.f) {
    w = w - 2.5f;
    p = 2.81022636e-08f;
    p = fmaf(p, w, 3.43273939e-07f);
    p = fmaf(p, w, -3.5233877e-06f);
    p = fmaf(p, w, -4.39150654e-06f);
    p = fmaf(p, w, 0.00021858087f);
    p = fmaf(p, w, -0.00125372503f);
    p = fmaf(p, w, -0.00417768164f);
    p = fmaf(p, w, 0.246640727f);
    p = fmaf(p, w, 1.50140941f);
  } else {
    w = sqrtf(w) - 3.f;
    p = -0.000200214257f;
    p = fmaf(p, w, 0.000100950558f);
    p = fmaf(p, w, 0.00134934322f);
    p = fmaf(p, w, -0.00367342844f);
    p = fmaf(p, w, 0.00573950773f);
    p = fmaf(p, w, -0.0076224613f);
    p = fmaf(p, w, 0.00943887047f);
    p = fmaf(p, w, 1.00167406f);
    p = fmaf(p, w, 2.83297682f);
  }
  return p * x;
}

// bits -> N(0,1) exactly as jax.random.normal (f32)
__device__ __forceinline__ float bits_to_normal(unsigned bits) {
  float f = __uint_as_float((bits >> 9) | 0x3f800000u) - 1.0f;  // [0,1)
  const float lo = -0.99999994f;       // nextafter(-1,0)
  float u = fmaf(f, 2.0f, lo);
  u = fmaxf(u, lo);
  return 1.41421356f * erfinv32(u);
}

// ---------- conversion / transpose kernels ----------
__global__ __launch_bounds__(256) void cvt_x(const float* __restrict__ in,
                                             unsigned short* __restrict__ out) {
  const int i = blockIdx.x * 256 + threadIdx.x;
  const float4 v = ((const float4*)in)[i];
  ushort4 o;
  o.x = f2bf(v.x); o.y = f2bf(v.y); o.z = f2bf(v.z); o.w = f2bf(v.w);
  ((ushort4*)out)[i] = o;
}

// in: [batch][R][C] f32  ->  out: [batch][C][R] bf16
__global__ __launch_bounds__(256) void transpose_bf16(
    const float* __restrict__ in, unsigned short* __restrict__ out, int R, int C) {
  __shared__ float tile[32][33];
  const int bz = blockIdx.z;
  in  += (size_t)bz * R * C;
  out += (size_t)bz * R * C;
  const int c0 = blockIdx.x * 32, r0 = blockIdx.y * 32;
  const int tx = threadIdx.x & 31, ty = threadIdx.x >> 5;  // 32x8
#pragma unroll
  for (int i = 0; i < 32; i += 8)
    tile[ty + i][tx] = in[(size_t)(r0 + ty + i) * C + c0 + tx];
  __syncthreads();
#pragma unroll
  for (int i = 0; i < 32; i += 8)
    out[(size_t)(c0 + ty + i) * R + r0 + tx] = f2bf(tile[tx][ty + i]);
}

// ---------- gating: mean/std/noise/top-k/softmax, all fp32 ----------
__global__ __launch_bounds__(256) void gating_kernel(
    const float* __restrict__ x, const float* __restrict__ Wg,
    const float* __restrict__ Wn, float* __restrict__ g) {
  __shared__ float xs[8][1024];
  __shared__ float partial[64][4][8];
  __shared__ float meanS[2][8][16];
  __shared__ float stdS[2][8][16];
  __shared__ float noisyS[2][8][16];
  const int tid = threadIdx.x;
  const int b0 = blockIdx.x * 8;
  for (int idx = tid; idx < 8 * 1024; idx += 256) {
    int r = idx >> 10, c = idx & 1023;
    xs[r][c] = x[(size_t)(b0 + r) * 1024 + c];
  }
  __syncthreads();
  {
    const int c = tid & 63;          // column id: t*32 + which*16 + e
    const int q = tid >> 6;          // K-partition 0..3
    const int t = c >> 5, which = (c >> 4) & 1, e = c & 15;
    const float* Wcol = (which ? Wn : Wg) + (size_t)t * 1024 * 16 + e;
    float acc[8] = {0, 0, 0, 0, 0, 0, 0, 0};
    const int i0 = q * 256;
    for (int i = i0; i < i0 + 256; ++i) {
      float w = Wcol[(size_t)i * 16];
#pragma unroll
      for (int r = 0; r < 8; ++r) acc[r] = fmaf(w, xs[r][i], acc[r]);
    }
#pragma unroll
    for (int r = 0; r < 8; ++r) partial[c][q][r] = acc[r];
  }
  __syncthreads();
  for (int idx = tid; idx < 512; idx += 256) {
    int c = idx >> 3, r = idx & 7;
    float s = partial[c][0][r] + partial[c][1][r] + partial[c][2][r] + partial[c][3][r];
    int t = c >> 5, which = (c >> 4) & 1, e = c & 15;
    if (which)  // softplus
      stdS[t][r][e] = fmaxf(s, 0.f) + log1pf(expf(-fabsf(s)));
    else
      meanS[t][r][e] = s;
  }
  __syncthreads();
  if (tid < 128) {
    int r = tid >> 4, e = tid & 15;
    unsigned p = (unsigned)((b0 + r) * 16 + e);
#pragma unroll
    for (int t = 0; t < 2; ++t) {
      unsigned n = (unsigned)t * 131072u + p;  // flat index into (T,B,E)
      unsigned y0, y1;
      threefry2x32(0u, 42u, 0u, n, y0, y1);    // partitionable: counter=(0, n)
      float nrm = bits_to_normal(y0 ^ y1);
      noisyS[t][r][e] = meanS[t][r][e] + nrm * stdS[t][r][e];
    }
  }
  __syncthreads();
  if (tid < 16) {
    int r = tid >> 1, t = tid & 1;
    float v[16];
#pragma unroll
    for (int e = 0; e < 16; ++e) v[e] = noisyS[t][r][e];
    float m0 = -1e30f, m1 = -1e30f, m2 = -1e30f, m3 = -1e30f;
#pragma unroll
    for (int e = 0; e < 16; ++e) {
      float val = v[e];
      if (val > m0) { m3 = m2; m2 = m1; m1 = m0; m0 = val; }
      else if (val > m1) { m3 = m2; m2 = m1; m1 = val; }
      else if (val > m2) { m3 = m2; m2 = val; }
      else if (val > m3) { m3 = val; }
    }
    float sum = 0.f, ge[16];
#pragma unroll
    for (int e = 0; e < 16; ++e) {
      if (v[e] >= m3) { ge[e] = expf(v[e] - m0); sum += ge[e]; }
      else ge[e] = 0.f;
    }
    float inv = 1.f / sum;
    float* grow = g + ((size_t)t * 8192 + (b0 + r)) * 16;
#pragma unroll
    for (int e = 0; e < 16; ++e) grow[e] = ge[e] * inv;
  }
}

// ---------- MoE dispatch metadata ----------
__global__ __launch_bounds__(256) void zero_counts(int* __restrict__ counts,
                                                   int n) {
  const int i = blockIdx.x * 256 + threadIdx.x;
  if (i < n) counts[i] = 0;
}

// per-(chunk,expert) row lists from g's exact-zero sparsity
// wave-aggregated: one atomic per (wave, expert) instead of per (row, expert)
__global__ __launch_bounds__(256) void build_lists(
    const float* __restrict__ g, int Bc, int* __restrict__ counts,
    int* __restrict__ lists, int* __restrict__ slotmap) {
  const int b = blockIdx.x * 256 + threadIdx.x;  // 8192 threads total
  const int lane = threadIdx.x & 63;
  const int chunk = b / Bc, bl = b % Bc;         // chunk is wave-uniform (Bc>=1024)
  float v0[16], v1[16];
  {
    const float4* p0 = (const float4*)(g + (size_t)b * 16);
    const float4* p1 = (const float4*)(g + ((size_t)8192 + b) * 16);
#pragma unroll
    for (int i = 0; i < 4; ++i) {
      ((float4*)v0)[i] = p0[i];
      ((float4*)v1)[i] = p1[i];
    }
  }
  int* cnt = counts + chunk * 16;
  int* lst = lists + (size_t)chunk * 16 * Bc;
  int* smp = slotmap + (size_t)chunk * 16 * Bc;
#pragma unroll
  for (int e = 0; e < 16; ++e) {
    const bool want = (v0[e] != 0.f) || (v1[e] != 0.f);
    const unsigned long long mask = __ballot(want);
    int base = 0;
    if (lane == 0) base = atomicAdd(&cnt[e], (int)__popcll(mask));
    base = __shfl(base, 0, 64);
    if (want) {
      const int slot = base + (int)__popcll(mask & ((1ULL << lane) - 1ULL));
      if (slot < Bc) {                 // defensive: never write OOB
        lst[e * Bc + slot] = b;        // global row index into x
        smp[e * Bc + bl] = slot;       // inverse map for combine
      }
    }
  }
}

// flatten live (e,bm) tiles, expert-major, into work[] + total per chunk.
__global__ __launch_bounds__(64) void build_work(
    const int* __restrict__ counts, int* __restrict__ work,
    int* __restrict__ totals, int gm1, int Bc) {
  const int chunk = blockIdx.x;
  if (threadIdx.x != 0) return;
  const int* cnt = counts + chunk * 16;
  int* w = work + chunk * gm1 * 16;
  int s = 0;
  for (int e = 0; e < 16; ++e) {
    int c = cnt[e];
    if (c < 0) c = 0;
    if (c > Bc) c = Bc;
    const int nt = (c + 127) >> 7;
    for (int t = 0; t < nt; ++t) w[s + t] = (e << 8) | t;
    s += nt;
  }
  totals[chunk] = s;
}

// ---------- row compaction: xg[e][slot][:] = xb[lists[e][slot]][:] ----------
__global__ __launch_bounds__(256) void gather_rows(
    const unsigned short* __restrict__ xb, const int* __restrict__ counts,
    const int* __restrict__ lists, unsigned short* __restrict__ xg, int Bc) {
  const int e = blockIdx.y;
  const int slot = blockIdx.x * 4 + (threadIdx.x >> 6);
  const int lane = threadIdx.x & 63;
  if (slot >= counts[e]) return;
  const int r = lists[(size_t)e * Bc + slot] & 8191;
  const float4* src = (const float4*)(xb + (size_t)r * 1024);
  float4* dst = (float4*)(xg + ((size_t)e * Bc + slot) * 1024);
  dst[lane] = src[lane];
  dst[lane + 64] = src[lane + 64];
}

// ---------- shared 3-stage K-loop (T3+T4: counted vmcnt, distance-2) ----------
// per step k: wait step-k loads (vmcnt(4): step k+1's 4 stay IN FLIGHT across
// the barrier) -> barrier -> issue step k+2 into buf[(k+2)%3] (WAR-safe: that
// buffer's reader, step k-1, finished before this barrier) -> compute buf[k%3].
// final step uses vmcnt(0) (no younger loads to count against).
// in-order vmem retirement means any compiler-issued early loads (counts/work)
// retire before the staging loads, so the counted wait stays correct.
#define GEMM_PIPE3_LOOP()                                                     \
  for (int k0 = 0; k0 < K; k0 += 32) {                                        \
    const int step = k0 >> 5;                                                 \
    const int cur = step % 3;                                                 \
    if (k0 + 32 < K) asm volatile("s_waitcnt vmcnt(4)" ::: "memory");         \
    else             asm volatile("s_waitcnt vmcnt(0)" ::: "memory");         \
    __builtin_amdgcn_s_barrier();                                             \
    asm volatile("" ::: "memory");                                            \
    if (k0 + 64 < K) {                                                        \
      const int pf = cur == 0 ? 2 : cur - 1;  /* (step+2)%3 */                \
      gl_lds16(gA0 + k0 + 64, &As[pf][lofsA0]);                               \
      gl_lds16(gA1 + k0 + 64, &As[pf][lofsA1]);                               \
      gl_lds16(gB0 + k0 + 64, &Bs[pf][lofsA0]);                               \
      gl_lds16(gB1 + k0 + 64, &Bs[pf][lofsA1]);                               \
    }                                                                         \
    bf16x8 af[4], bfr[4];                                                     \
    _Pragma("unroll")                                                         \
    for (int mt = 0; mt < 4; ++mt)                                            \
      af[mt] = *(const bf16x8*)&As[cur][(wm * 64 + mt * 16 + frow) * 32 + fk];\
    _Pragma("unroll")                                                         \
    for (int nt = 0; nt < 4; ++nt)                                            \
      bfr[nt] = *(const bf16x8*)&Bs[cur][(wn * 64 + nt * 16 + frow) * 32 + fk];\
    _Pragma("unroll")                                                         \
    for (int mt = 0; mt < 4; ++mt)                                            \
      _Pragma("unroll")                                                       \
      for (int nt = 0; nt < 4; ++nt)                                          \
        acc[mt][nt] = __builtin_amdgcn_mfma_f32_16x16x32_bf16(                \
            af[mt], bfr[nt], acc[mt][nt], 0, 0, 0);                           \
  }

#define GEMM_PIPE3_PROLOGUE()                                                 \
  gl_lds16(gA0, &As[0][lofsA0]);                                              \
  gl_lds16(gA1, &As[0][lofsA1]);                                              \
  gl_lds16(gB0, &Bs[0][lofsA0]);                                              \
  gl_lds16(gB1, &Bs[0][lofsA1]);                                              \
  if (K > 32) {                                                               \
    gl_lds16(gA0 + 32, &As[1][lofsA0]);                                       \
    gl_lds16(gA1 + 32, &As[1][lofsA1]);                                       \
    gl_lds16(gB0 + 32, &Bs[1][lofsA0]);                                       \
    gl_lds16(gB1 + 32, &Bs[1][lofsA1]);                                       \
  }

// ---------- dense bf16 MFMA GEMM with XCD chunked swizzle (towers) ----------
template <bool RELU, bool OUT_BF16>
__global__ __launch_bounds__(256) void gemm_bt(
    const unsigned short* __restrict__ A, int lda, long long strideA,
    const unsigned short* __restrict__ Bt, int ldb, long long strideB,
    void* __restrict__ Cv, int ldc, long long strideC,
    const float* __restrict__ bias, int strideBias, int K,
    int gm, int gn) {
  __shared__ __align__(16) unsigned short As[3][128 * 32];
  __shared__ __align__(16) unsigned short Bs[3][128 * 32];
  const int tid = threadIdx.x;
  const int w = tid >> 6, lane = tid & 63;
  const int wm = w >> 1, wn = w & 1;

  int swz = blockIdx.x;
  const int nwg = gridDim.x;
  if ((nwg & 7) == 0) swz = (swz & 7) * (nwg >> 3) + (swz >> 3);
  const int bm = swz % gm;
  const int tmp = swz / gm;
  const int bn = tmp % gn;
  const int bz = tmp / gn;

  const unsigned short* Ab = A + (size_t)bz * strideA + (size_t)bm * 128 * lda;
  const unsigned short* Bb = Bt + (size_t)bz * strideB + (size_t)bn * 128 * ldb;

  const int srow = lane >> 2;
  const int scol = (lane & 3) * 8;
  const unsigned short* gA0 = Ab + (size_t)(w * 32 + srow) * lda + scol;
  const unsigned short* gA1 = gA0 + (size_t)16 * lda;
  const unsigned short* gB0 = Bb + (size_t)(w * 32 + srow) * ldb + scol;
  const unsigned short* gB1 = gB0 + (size_t)16 * ldb;
  const int lofsA0 = (w * 32) * 32;
  const int lofsA1 = (w * 32 + 16) * 32;

  f32x4 acc[4][4] = {};
  const int frow = lane & 15;
  const int fk = (lane >> 4) * 8;

  GEMM_PIPE3_PROLOGUE()
  GEMM_PIPE3_LOOP()

  const int crow = (lane >> 4) * 4;
  const int ccol = lane & 15;
  const float* brow = bias + (size_t)bz * strideBias + (size_t)bn * 128;
#pragma unroll
  for (int nt = 0; nt < 4; ++nt) {
    int col = wn * 64 + nt * 16 + ccol;
    float bv = brow[col];
#pragma unroll
    for (int mt = 0; mt < 4; ++mt) {
      f32x4 v = acc[mt][nt];
#pragma unroll
      for (int r = 0; r < 4; ++r) {
        float val = v[r] + bv;
        if (RELU) val = fmaxf(val, 0.f);
        size_t row = (size_t)bm * 128 + wm * 64 + mt * 16 + crow + r;
        size_t off = (size_t)bz * strideC + row * ldc + (size_t)bn * 128 + col;
        if (OUT_BF16) ((unsigned short*)Cv)[off] = f2bf(val);
        else          ((float*)Cv)[off] = val;
      }
    }
  }
}

// ---------- sparse bf16 MFMA GEMM over live-tile work list ----------
template <bool RELU>
__global__ __launch_bounds__(256) void gemm_sparse(
    const unsigned short* __restrict__ A, int lda, long long strideA,
    const unsigned short* __restrict__ Bt, int ldb, long long strideB,
    unsigned short* __restrict__ C, int ldc, long long strideC,
    const float* __restrict__ bias, int strideBias, int K,
    const int* __restrict__ counts, const int* __restrict__ work,
    const int* __restrict__ totalp, int lgn, int gm1, int Bc) {
  __shared__ __align__(16) unsigned short As[3][128 * 32];
  __shared__ __align__(16) unsigned short Bs[3][128 * 32];
  const int tid = threadIdx.x;
  const int w = tid >> 6, lane = tid & 63;
  const int wm = w >> 1, wn = w & 1;

  int T = (*totalp) << lgn;            // live block count
  const int nwg = gridDim.x;
  if (T > nwg) T = nwg;                // defensive
  const int j = blockIdx.x;
  const int x = j & 7, rank = j >> 3;  // x ~ XCD (dispatch round-robin)
  const int q = T >> 3, r = T & 7;
  const int quota = q + (x < r ? 1 : 0);
  if (rank >= quota) return;           // uniform early-exit (no barrier yet)
  const int i = (x < r ? x * (q + 1) : r * (q + 1) + (x - r) * q) + rank;
  const int tile = i >> lgn, bn = i & ((1 << lgn) - 1);
  const int wentry = work[tile];
  const int bz = (wentry >> 8) & 15;
  const int bm = wentry & (gm1 - 1);   // gm1 is a power of two
  int mcount = counts[bz];
  if (mcount > Bc) mcount = Bc;        // defensive clamp
  if (mcount < 0) mcount = 0;

  const unsigned short* Ab = A + (size_t)bz * strideA + (size_t)bm * 128 * lda;
  const unsigned short* Bb = Bt + (size_t)bz * strideB + (size_t)bn * 128 * ldb;

  const int srow = lane >> 2;
  const int scol = (lane & 3) * 8;
  const unsigned short* gA0 = Ab + (size_t)(w * 32 + srow) * lda + scol;
  const unsigned short* gA1 = gA0 + (size_t)16 * lda;
  const unsigned short* gB0 = Bb + (size_t)(w * 32 + srow) * ldb + scol;
  const unsigned short* gB1 = gB0 + (size_t)16 * ldb;
  const int lofsA0 = (w * 32) * 32;
  const int lofsA1 = (w * 32 + 16) * 32;

  f32x4 acc[4][4] = {};
  const int frow = lane & 15;
  const int fk = (lane >> 4) * 8;

  GEMM_PIPE3_PROLOGUE()
  GEMM_PIPE3_LOOP()

  const int crow = (lane >> 4) * 4;
  const int ccol = lane & 15;
  const float* brow = bias + (size_t)bz * strideBias + (size_t)bn * 128;
#pragma unroll
  for (int nt = 0; nt < 4; ++nt) {
    int col = wn * 64 + nt * 16 + ccol;
    float bv = brow[col];
#pragma unroll
    for (int mt = 0; mt < 4; ++mt) {
      f32x4 v = acc[mt][nt];
#pragma unroll
      for (int r = 0; r < 4; ++r) {
        float val = v[r] + bv;
        if (RELU) val = fmaxf(val, 0.f);
        int row = bm * 128 + wm * 64 + mt * 16 + crow + r;
        if (row < mcount) {
          size_t off = (size_t)bz * strideC + (size_t)row * ldc +
                       (size_t)bn * 128 + col;
          C[off] = f2bf(val);
        }
      }
    }
  }
}

// ---------- gate combine (chunked, compacted eo via slotmap) ----------
__global__ __launch_bounds__(128) void combine_kernel(
    const unsigned short* __restrict__ eo, const float* __restrict__ g,
    unsigned short* __restrict__ go, int b0, long long strideE,
    const int* __restrict__ slotmap, int Bc) {
  const int bl = blockIdx.x, t = blockIdx.y;
  const int b = b0 + bl;
  const int o = threadIdx.x;
  const float* grow = g + ((size_t)t * 8192 + b) * 16;
  float a0 = 0, a1 = 0, a2 = 0, a3 = 0;
  for (int e = 0; e < 16; ++e) {
    float ge = grow[e];
    if (ge != 0.f) {                      // block-uniform branch
      const int slot = slotmap[e * Bc + bl] & (Bc - 1);
      const unsigned short* row = eo + (size_t)e * strideE + (size_t)slot * 512;
      a0 = fmaf(ge, bf2f(row[o]), a0);
      a1 = fmaf(ge, bf2f(row[o + 128]), a1);
      a2 = fmaf(ge, bf2f(row[o + 256]), a2);
      a3 = fmaf(ge, bf2f(row[o + 384]), a3);
    }
  }
  unsigned short* orow = go + ((size_t)t * 8192 + b) * 512;
  orow[o] = f2bf(a0); orow[o + 128] = f2bf(a1);
  orow[o + 256] = f2bf(a2); orow[o + 384] = f2bf(a3);
}

// ---------- final: out[t*8192+b] = dot(t2[t][b][:256], Wh3[t]) + bh3[t] ----------
__global__ __launch_bounds__(256) void final_dot(const float* __restrict__ t2,
                                                 const float* __restrict__ Wh3,
                                                 const float* __restrict__ bh3,
                                                 float* __restrict__ out) {
  const int row = blockIdx.x * 4 + (threadIdx.x >> 6);  // one wave per row
  const int lane = threadIdx.x & 63;
  const int t = row >> 13;
  const float* trow = t2 + (size_t)row * 256;
  const float* w = Wh3 + t * 256;
  float s = 0.f;
#pragma unroll
  for (int j = 0; j < 4; ++j) s = fmaf(trow[lane + j * 64], w[lane + j * 64], s);
#pragma unroll
  for (int off = 32; off > 0; off >>= 1) s += __shfl_down(s, off, 64);
  if (lane == 0) out[row] = s + bh3[t];
}

// ---------- orchestration ----------
extern "C" void kernel_launch(void* const* d_in, const int* in_sizes, int n_in,
                              void* d_out, int out_size, void* d_ws, size_t ws_size,
                              hipStream_t stream) {
  (void)in_sizes; (void)n_in; (void)out_size;
  const float* x   = (const float*)d_in[0];
  const float* We1 = (const float*)d_in[1];
  const float* be1 = (const float*)d_in[2];
  const float* We2 = (const float*)d_in[3];
  const float* be2 = (const float*)d_in[4];
  const float* Wg  = (const float*)d_in[5];
  const float* Wn  = (const float*)d_in[6];
  const float* Wh1 = (const float*)d_in[7];
  const float* bh1 = (const float*)d_in[8];
  const float* Wh2 = (const float*)d_in[9];
  const float* bh2 = (const float*)d_in[10];
  const float* Wh3 = (const float*)d_in[11];
  const float* bh3 = (const float*)d_in[12];

  auto al = [](size_t v) { return (v + 255) & ~(size_t)255; };
  const size_t sz_xb   = al((size_t)8192 * 1024 * 2);
  const size_t sz_We1t = al((size_t)16 * 1024 * 1024 * 2);
  const size_t sz_We2t = al((size_t)16 * 512 * 1024 * 2);
  const size_t sz_Wh1t = al((size_t)2 * 512 * 512 * 2);
  const size_t sz_Wh2t = al((size_t)2 * 256 * 512 * 2);
  const size_t sz_g    = al((size_t)2 * 8192 * 16 * 4);
  const size_t sz_go   = al((size_t)2 * 8192 * 512 * 2);
  const size_t sz_cnt  = al((size_t)8 * 16 * 4);
  const size_t sz_lst  = al((size_t)16 * 8192 * 4);
  const size_t sz_smp  = al((size_t)16 * 8192 * 4);
  const size_t sz_wrk  = al((size_t)1024 * 4);
  const size_t sz_tot  = al((size_t)8 * 4);
  const size_t fixed = sz_xb + sz_We1t + sz_We2t + sz_Wh1t + sz_Wh2t + sz_g +
                       sz_go + sz_cnt + sz_lst + sz_smp + sz_wrk + sz_tot;
  const size_t sz_t1 = al((size_t)2 * 8192 * 512 * 2);   // bf16
  const size_t sz_t2 = al((size_t)2 * 8192 * 256 * 4);   // f32
  const size_t sz_t12 = sz_t1 + sz_t2;

  // region hosts xg (aliased by eo after FC1) + h; later aliased by t1/t2
  int Bc = 1024;
  {
    const int cands[4] = {8192, 4096, 2048, 1024};
    for (int ci = 0; ci < 4; ++ci) {
      int c = cands[ci];
      size_t region = 2 * al((size_t)16 * c * 1024 * 2);
      if (region < sz_t12) region = sz_t12;
      if (fixed + region <= ws_size) { Bc = c; break; }
    }
  }
  const size_t sz_hc = al((size_t)16 * Bc * 1024 * 2);
  const int nchunk = 8192 / Bc;
  const int gm1 = Bc / 128;            // power of two

  char* ws = (char*)d_ws;
  size_t off = 0;
  auto carve = [&](size_t bytes) -> char* { char* p = ws + off; off += bytes; return p; };
  unsigned short* xb   = (unsigned short*)carve(sz_xb);
  unsigned short* We1t = (unsigned short*)carve(sz_We1t);
  unsigned short* We2t = (unsigned short*)carve(sz_We2t);
  unsigned short* Wh1t = (unsigned short*)carve(sz_Wh1t);
  unsigned short* Wh2t = (unsigned short*)carve(sz_Wh2t);
  float* g             = (float*)carve(sz_g);
  unsigned short* go   = (unsigned short*)carve(sz_go);
  int* counts          = (int*)carve(sz_cnt);
  int* lists           = (int*)carve(sz_lst);
  int* slotmap         = (int*)carve(sz_smp);
  int* work            = (int*)carve(sz_wrk);
  int* totals          = (int*)carve(sz_tot);
  char* region         = ws + off;
  unsigned short* xg   = (unsigned short*)region;            // [16][Bc][1024] compacted x
  unsigned short* eo   = (unsigned short*)region;            // [16][Bc][512] (aliases xg)
  unsigned short* h    = (unsigned short*)(region + sz_hc);  // [16][Bc][1024] compacted
  unsigned short* t1   = (unsigned short*)region;            // aliases (dead by towers)
  float* t2            = (float*)(region + sz_t1);

  // prep: casts + weight transposes (B operands need N x K)
  cvt_x<<<8192, 256, 0, stream>>>(x, xb);
  transpose_bf16<<<dim3(32, 32, 16), 256, 0, stream>>>(We1, We1t, 1024, 1024);
  transpose_bf16<<<dim3(16, 32, 16), 256, 0, stream>>>(We2, We2t, 1024, 512);
  transpose_bf16<<<dim3(16, 16, 2), 256, 0, stream>>>(Wh1, Wh1t, 512, 512);
  transpose_bf16<<<dim3(8, 16, 2), 256, 0, stream>>>(Wh2, Wh2t, 512, 256);

  // gating (fp32, threefry noise, top-4 softmax)
  gating_kernel<<<1024, 256, 0, stream>>>(x, Wg, Wn, g);
  // routing metadata
  zero_counts<<<1, 256, 0, stream>>>(counts, nchunk * 16);
  build_lists<<<32, 256, 0, stream>>>(g, Bc, counts, lists, slotmap);
  build_work<<<nchunk, 64, 0, stream>>>(counts, work, totals, gm1, Bc);

  // expert pipeline, chunked over batch; only routed tiles are computed
  for (int b0 = 0; b0 < 8192; b0 += Bc) {
    const int chunk = b0 / Bc;
    const int* cnt = counts + chunk * 16;
    const int* lst = lists + (size_t)chunk * 16 * Bc;
    const int* smp = slotmap + (size_t)chunk * 16 * Bc;
    const int* wrk = work + chunk * gm1 * 16;
    const int* tot = totals + chunk;
    // compact routed x rows (streaming gather; latency hidden by TLP)
    gather_rows<<<dim3(Bc / 4, 16), 256, 0, stream>>>(xb, cnt, lst, xg, Bc);
    // FC1 (sparse): h[e][slot][:] = relu(xg[e][slot] @ We1[e] + be1[e]); gn=8
    gemm_sparse<true><<<gm1 * 16 * 8, 256, 0, stream>>>(
        xg, 1024, (long long)Bc * 1024,
        We1t, 1024, (long long)1024 * 1024,
        h, 1024, (long long)Bc * 1024, be1, 1024, 1024,
        cnt, wrk, tot, 3, gm1, Bc);
    // FC2 (sparse): eo[e][slot][:] = h[e][slot] @ We2[e] + be2[e]; gn=4
    // (eo aliases xg, dead after FC1)
    gemm_sparse<false><<<gm1 * 16 * 4, 256, 0, stream>>>(
        h, 1024, (long long)Bc * 1024,
        We2t, 1024, (long long)512 * 1024,
        eo, 512, (long long)Bc * 512, be2, 512, 1024,
        cnt, wrk, tot, 2, gm1, Bc);
    // combine into go rows [b0, b0+Bc) via slotmap
    combine_kernel<<<dim3(Bc, 2), 128, 0, stream>>>(
        eo, g, go, b0, (long long)Bc * 512, smp, Bc);
  }

  // towers (full batch, dense + XCD swizzle)
  gemm_bt<true, true><<<64 * 4 * 2, 256, 0, stream>>>(
      go, 512, (long long)8192 * 512, Wh1t, 512, (long long)512 * 512,
      t1, 512, (long long)8192 * 512, bh1, 512, 512,
      64, 4);
  gemm_bt<true, false><<<64 * 2 * 2, 256, 0, stream>>>(
      t1, 512, (long long)8192 * 512, Wh2t, 512, (long long)256 * 512,
      t2, 256, (long long)8192 * 256, bh2, 256, 512,
      64, 2);

  final_dot<<<4096, 256, 0, stream>>>(t2, Wh3, bh3, (float*)d_out);
}

// Round 10
// 702.242 us; speedup vs baseline: 1.1036x; 1.1036x over previous
//
#include <hip/hip_runtime.h>

#define AS1 __attribute__((address_space(1)))
#define AS3 __attribute__((address_space(3)))

typedef __bf16 bf16x8 __attribute__((ext_vector_type(8)));
typedef float f32x4 __attribute__((ext_vector_type(4)));

// ---------- small helpers ----------
__device__ __forceinline__ unsigned short f2bf(float f) {
  unsigned u = __float_as_uint(f);
  u += 0x7FFFu + ((u >> 16) & 1u);   // RNE
  return (unsigned short)(u >> 16);
}
__device__ __forceinline__ float bf2f(unsigned short u) {
  return __uint_as_float(((unsigned)u) << 16);
}

__device__ __forceinline__ void gl_lds16(const void* g, void* l) {
  // async global->LDS, 16B per lane; LDS dest = wave-uniform base + lane*16
  __builtin_amdgcn_global_load_lds((const AS1 unsigned int*)g,
                                   (AS3 unsigned int*)l, 16, 0, 0);
}

// ---------- Threefry-2x32 (20 rounds), JAX-compatible ----------
__device__ __forceinline__ unsigned rotl32(unsigned v, int s) {
  return (v << s) | (v >> (32 - s));
}
__device__ __forceinline__ void threefry2x32(unsigned k0, unsigned k1,
                                             unsigned x0, unsigned x1,
                                             unsigned& o0, unsigned& o1) {
  const unsigned ks2 = k0 ^ k1 ^ 0x1BD11BDAu;
  x0 += k0; x1 += k1;
  x0 += x1; x1 = rotl32(x1, 13); x1 ^= x0;
  x0 += x1; x1 = rotl32(x1, 15); x1 ^= x0;
  x0 += x1; x1 = rotl32(x1, 26); x1 ^= x0;
  x0 += x1; x1 = rotl32(x1, 6);  x1 ^= x0;
  x0 += k1; x1 += ks2 + 1u;
  x0 += x1; x1 = rotl32(x1, 17); x1 ^= x0;
  x0 += x1; x1 = rotl32(x1, 29); x1 ^= x0;
  x0 += x1; x1 = rotl32(x1, 16); x1 ^= x0;
  x0 += x1; x1 = rotl32(x1, 24); x1 ^= x0;
  x0 += ks2; x1 += k0 + 2u;
  x0 += x1; x1 = rotl32(x1, 13); x1 ^= x0;
  x0 += x1; x1 = rotl32(x1, 15); x1 ^= x0;
  x0 += x1; x1 = rotl32(x1, 26); x1 ^= x0;
  x0 += x1; x1 = rotl32(x1, 6);  x1 ^= x0;
  x0 += k0; x1 += k1 + 3u;
  x0 += x1; x1 = rotl32(x1, 17); x1 ^= x0;
  x0 += x1; x1 = rotl32(x1, 29); x1 ^= x0;
  x0 += x1; x1 = rotl32(x1, 16); x1 ^= x0;
  x0 += x1; x1 = rotl32(x1, 24); x1 ^= x0;
  x0 += k1; x1 += ks2 + 4u;
  x0 += x1; x1 = rotl32(x1, 13); x1 ^= x0;
  x0 += x1; x1 = rotl32(x1, 15); x1 ^= x0;
  x0 += x1; x1 = rotl32(x1, 26); x1 ^= x0;
  x0 += x1; x1 = rotl32(x1, 6);  x1 ^= x0;
  o0 = x0 + ks2; o1 = x1 + k0 + 5u;
}

// XLA f32 erf_inv (Giles polynomial)
__device__ __forceinline__ float erfinv32(float x) {
  float w = -log1pf(-x * x);
  float p;
  if (w < 5.f) {
    w = w - 2.5f;
    p = 2.81022636e-08f;
    p = fmaf(p, w, 3.43273939e-07f);
    p = fmaf(p, w, -3.5233877e-06f);
    p = fmaf(p, w, -4.39150654e-06f);
    p = fmaf(p, w, 0.00021858087f);
    p = fmaf(p, w, -0.00125372503f);
    p = fmaf(p, w, -0.00417768164f);
    p = fmaf(p, w, 0.246640727f);
    p = fmaf(p, w, 1.50140941f);
  } else {
    w = sqrtf(w) - 3.f;
    p = -0.000200214257f;
    p = fmaf(p, w, 0.000100950558f);
    p = fmaf(p, w, 0.00134934322f);
    p = fmaf(p, w, -0.00367342844f);
    p = fmaf(p, w, 0.00573950773f);
    p = fmaf(p, w, -0.0076224613f);
    p = fmaf(p, w, 0.00943887047f);
    p = fmaf(p, w, 1.00167406f);
    p = fmaf(p, w, 2.83297682f);
  }
  return p * x;
}

// bits -> N(0,1) exactly as jax.random.normal (f32)
__device__ __forceinline__ float bits_to_normal(unsigned bits) {
  float f = __uint_as_float((bits >> 9) | 0x3f800000u) - 1.0f;  // [0,1)
  const float lo = -0.99999994f;       // nextafter(-1,0)
  float u = fmaf(f, 2.0f, lo);
  u = fmaxf(u, lo);
  return 1.41421356f * erfinv32(u);
}

// ---------- conversion / transpose kernels ----------
__global__ __launch_bounds__(256) void cvt_x(const float* __restrict__ in,
                                             unsigned short* __restrict__ out) {
  const int i = blockIdx.x * 256 + threadIdx.x;
  const float4 v = ((const float4*)in)[i];
  ushort4 o;
  o.x = f2bf(v.x); o.y = f2bf(v.y); o.z = f2bf(v.z); o.w = f2bf(v.w);
  ((ushort4*)out)[i] = o;
}

// in: [batch][R][C] f32  ->  out: [batch][C][R] bf16
__global__ __launch_bounds__(256) void transpose_bf16(
    const float* __restrict__ in, unsigned short* __restrict__ out, int R, int C) {
  __shared__ float tile[32][33];
  const int bz = blockIdx.z;
  in  += (size_t)bz * R * C;
  out += (size_t)bz * R * C;
  const int c0 = blockIdx.x * 32, r0 = blockIdx.y * 32;
  const int tx = threadIdx.x & 31, ty = threadIdx.x >> 5;  // 32x8
#pragma unroll
  for (int i = 0; i < 32; i += 8)
    tile[ty + i][tx] = in[(size_t)(r0 + ty + i) * C + c0 + tx];
  __syncthreads();
#pragma unroll
  for (int i = 0; i < 32; i += 8)
    out[(size_t)(c0 + ty + i) * R + r0 + tx] = f2bf(tile[tx][ty + i]);
}

// ---------- gating: mean/std/noise/top-k/softmax, all fp32 ----------
__global__ __launch_bounds__(256) void gating_kernel(
    const float* __restrict__ x, const float* __restrict__ Wg,
    const float* __restrict__ Wn, float* __restrict__ g) {
  __shared__ float xs[8][1024];
  __shared__ float partial[64][4][8];
  __shared__ float meanS[2][8][16];
  __shared__ float stdS[2][8][16];
  __shared__ float noisyS[2][8][16];
  const int tid = threadIdx.x;
  const int b0 = blockIdx.x * 8;
  for (int idx = tid; idx < 8 * 1024; idx += 256) {
    int r = idx >> 10, c = idx & 1023;
    xs[r][c] = x[(size_t)(b0 + r) * 1024 + c];
  }
  __syncthreads();
  {
    const int c = tid & 63;          // column id: t*32 + which*16 + e
    const int q = tid >> 6;          // K-partition 0..3
    const int t = c >> 5, which = (c >> 4) & 1, e = c & 15;
    const float* Wcol = (which ? Wn : Wg) + (size_t)t * 1024 * 16 + e;
    float acc[8] = {0, 0, 0, 0, 0, 0, 0, 0};
    const int i0 = q * 256;
    for (int i = i0; i < i0 + 256; ++i) {
      float w = Wcol[(size_t)i * 16];
#pragma unroll
      for (int r = 0; r < 8; ++r) acc[r] = fmaf(w, xs[r][i], acc[r]);
    }
#pragma unroll
    for (int r = 0; r < 8; ++r) partial[c][q][r] = acc[r];
  }
  __syncthreads();
  for (int idx = tid; idx < 512; idx += 256) {
    int c = idx >> 3, r = idx & 7;
    float s = partial[c][0][r] + partial[c][1][r] + partial[c][2][r] + partial[c][3][r];
    int t = c >> 5, which = (c >> 4) & 1, e = c & 15;
    if (which)  // softplus
      stdS[t][r][e] = fmaxf(s, 0.f) + log1pf(expf(-fabsf(s)));
    else
      meanS[t][r][e] = s;
  }
  __syncthreads();
  if (tid < 128) {
    int r = tid >> 4, e = tid & 15;
    unsigned p = (unsigned)((b0 + r) * 16 + e);
#pragma unroll
    for (int t = 0; t < 2; ++t) {
      unsigned n = (unsigned)t * 131072u + p;  // flat index into (T,B,E)
      unsigned y0, y1;
      threefry2x32(0u, 42u, 0u, n, y0, y1);    // partitionable: counter=(0, n)
      float nrm = bits_to_normal(y0 ^ y1);
      noisyS[t][r][e] = meanS[t][r][e] + nrm * stdS[t][r][e];
    }
  }
  __syncthreads();
  if (tid < 16) {
    int r = tid >> 1, t = tid & 1;
    float v[16];
#pragma unroll
    for (int e = 0; e < 16; ++e) v[e] = noisyS[t][r][e];
    float m0 = -1e30f, m1 = -1e30f, m2 = -1e30f, m3 = -1e30f;
#pragma unroll
    for (int e = 0; e < 16; ++e) {
      float val = v[e];
      if (val > m0) { m3 = m2; m2 = m1; m1 = m0; m0 = val; }
      else if (val > m1) { m3 = m2; m2 = m1; m1 = val; }
      else if (val > m2) { m3 = m2; m2 = val; }
      else if (val > m3) { m3 = val; }
    }
    float sum = 0.f, ge[16];
#pragma unroll
    for (int e = 0; e < 16; ++e) {
      if (v[e] >= m3) { ge[e] = expf(v[e] - m0); sum += ge[e]; }
      else ge[e] = 0.f;
    }
    float inv = 1.f / sum;
    float* grow = g + ((size_t)t * 8192 + (b0 + r)) * 16;
#pragma unroll
    for (int e = 0; e < 16; ++e) grow[e] = ge[e] * inv;
  }
}

// ---------- MoE dispatch metadata ----------
__global__ __launch_bounds__(256) void zero_counts(int* __restrict__ counts,
                                                   int n) {
  const int i = blockIdx.x * 256 + threadIdx.x;
  if (i < n) counts[i] = 0;
}

// per-(chunk,expert) row lists from g's exact-zero sparsity
// wave-aggregated: one atomic per (wave, expert) instead of per (row, expert)
__global__ __launch_bounds__(256) void build_lists(
    const float* __restrict__ g, int Bc, int* __restrict__ counts,
    int* __restrict__ lists, int* __restrict__ slotmap) {
  const int b = blockIdx.x * 256 + threadIdx.x;  // 8192 threads total
  const int lane = threadIdx.x & 63;
  const int chunk = b / Bc, bl = b % Bc;         // chunk is wave-uniform (Bc>=1024)
  float v0[16], v1[16];
  {
    const float4* p0 = (const float4*)(g + (size_t)b * 16);
    const float4* p1 = (const float4*)(g + ((size_t)8192 + b) * 16);
#pragma unroll
    for (int i = 0; i < 4; ++i) {
      ((float4*)v0)[i] = p0[i];
      ((float4*)v1)[i] = p1[i];
    }
  }
  int* cnt = counts + chunk * 16;
  int* lst = lists + (size_t)chunk * 16 * Bc;
  int* smp = slotmap + (size_t)chunk * 16 * Bc;
#pragma unroll
  for (int e = 0; e < 16; ++e) {
    const bool want = (v0[e] != 0.f) || (v1[e] != 0.f);
    const unsigned long long mask = __ballot(want);
    int base = 0;
    if (lane == 0) base = atomicAdd(&cnt[e], (int)__popcll(mask));
    base = __shfl(base, 0, 64);
    if (want) {
      const int slot = base + (int)__popcll(mask & ((1ULL << lane) - 1ULL));
      if (slot < Bc) {                 // defensive: never write OOB
        lst[e * Bc + slot] = b;        // global row index into x
        smp[e * Bc + bl] = slot;       // inverse map for combine
      }
    }
  }
}

// flatten live (e,bm) tiles expert-major into work[] + padded per-expert
// row offsets (compact allocation: capacity cap = 8*Bc + 2048 rows).
__global__ __launch_bounds__(64) void build_work(
    const int* __restrict__ counts, int* __restrict__ work,
    int* __restrict__ totals, int* __restrict__ offsets,
    int gm1, int Bc, int cap) {
  const int chunk = blockIdx.x;
  if (threadIdx.x != 0) return;
  const int* cnt = counts + chunk * 16;
  int* w = work + chunk * gm1 * 16;
  int* offs = offsets + chunk * 16;
  int s = 0;      // tile index
  int rows = 0;   // padded row offset
  for (int e = 0; e < 16; ++e) {
    int c = cnt[e];
    if (c < 0) c = 0;
    if (c > Bc) c = Bc;
    int o = rows;
    if (o > cap - Bc) o = cap - Bc;   // defensive: expert writes <= Bc rows
    offs[e] = o;
    const int nt = (c + 127) >> 7;
    for (int t = 0; t < nt; ++t) w[s + t] = (e << 8) | t;
    s += nt;
    rows += nt << 7;                  // pad to 128 rows
  }
  totals[chunk] = s;
}

// ---------- row compaction: xg[offs[e]+slot][:] = xb[lists[e][slot]][:] ----------
__global__ __launch_bounds__(256) void gather_rows(
    const unsigned short* __restrict__ xb, const int* __restrict__ counts,
    const int* __restrict__ lists, const int* __restrict__ offs,
    unsigned short* __restrict__ xg, int Bc, int cap) {
  const int e = blockIdx.y;
  const int slot = blockIdx.x * 4 + (threadIdx.x >> 6);
  const int lane = threadIdx.x & 63;
  int c = counts[e];
  if (c > Bc) c = Bc;
  if (slot >= c) return;
  int o = offs[e];
  if (o < 0) o = 0;
  if (o > cap - Bc) o = cap - Bc;
  const int r = lists[(size_t)e * Bc + slot] & 8191;
  const float4* src = (const float4*)(xb + (size_t)r * 1024);
  float4* dst = (float4*)(xg + ((size_t)o + slot) * 1024);
  dst[lane] = src[lane];
  dst[lane + 64] = src[lane + 64];
}

// ---------- shared double-buffered K-loop (2-phase; r7-proven) ----------
// stage next K-tile into buf[1-c] BEFORE computing buf[c]; one barrier/K-step.
#define GEMM_DBUF_LOOP()                                                      \
  for (int k0 = 0; k0 < K; k0 += 32) {                                        \
    const int cur = (k0 >> 5) & 1;                                            \
    if (k0 + 32 < K) {                                                        \
      const int nxt = cur ^ 1;                                                \
      gl_lds16(gA0 + k0 + 32, &As[nxt][lofsA0]);                              \
      gl_lds16(gA1 + k0 + 32, &As[nxt][lofsA1]);                              \
      gl_lds16(gB0 + k0 + 32, &Bs[nxt][lofsA0]);                              \
      gl_lds16(gB1 + k0 + 32, &Bs[nxt][lofsA1]);                              \
    }                                                                         \
    bf16x8 af[4], bfr[4];                                                     \
    _Pragma("unroll")                                                         \
    for (int mt = 0; mt < 4; ++mt)                                            \
      af[mt] = *(const bf16x8*)&As[cur][(wm * 64 + mt * 16 + frow) * 32 + fk];\
    _Pragma("unroll")                                                         \
    for (int nt = 0; nt < 4; ++nt)                                            \
      bfr[nt] = *(const bf16x8*)&Bs[cur][(wn * 64 + nt * 16 + frow) * 32 + fk];\
    _Pragma("unroll")                                                         \
    for (int mt = 0; mt < 4; ++mt)                                            \
      _Pragma("unroll")                                                       \
      for (int nt = 0; nt < 4; ++nt)                                          \
        acc[mt][nt] = __builtin_amdgcn_mfma_f32_16x16x32_bf16(                \
            af[mt], bfr[nt], acc[mt][nt], 0, 0, 0);                           \
    __syncthreads();                                                          \
  }

// ---------- dense bf16 MFMA GEMM with XCD chunked swizzle (towers) ----------
template <bool RELU, bool OUT_BF16>
__global__ __launch_bounds__(256) void gemm_bt(
    const unsigned short* __restrict__ A, int lda, long long strideA,
    const unsigned short* __restrict__ Bt, int ldb, long long strideB,
    void* __restrict__ Cv, int ldc, long long strideC,
    const float* __restrict__ bias, int strideBias, int K,
    int gm, int gn) {
  __shared__ __align__(16) unsigned short As[2][128 * 32];
  __shared__ __align__(16) unsigned short Bs[2][128 * 32];
  const int tid = threadIdx.x;
  const int w = tid >> 6, lane = tid & 63;
  const int wm = w >> 1, wn = w & 1;

  int swz = blockIdx.x;
  const int nwg = gridDim.x;
  if ((nwg & 7) == 0) swz = (swz & 7) * (nwg >> 3) + (swz >> 3);
  const int bm = swz % gm;
  const int tmp = swz / gm;
  const int bn = tmp % gn;
  const int bz = tmp / gn;

  const unsigned short* Ab = A + (size_t)bz * strideA + (size_t)bm * 128 * lda;
  const unsigned short* Bb = Bt + (size_t)bz * strideB + (size_t)bn * 128 * ldb;

  const int srow = lane >> 2;
  const int scol = (lane & 3) * 8;
  const unsigned short* gA0 = Ab + (size_t)(w * 32 + srow) * lda + scol;
  const unsigned short* gA1 = gA0 + (size_t)16 * lda;
  const unsigned short* gB0 = Bb + (size_t)(w * 32 + srow) * ldb + scol;
  const unsigned short* gB1 = gB0 + (size_t)16 * ldb;
  const int lofsA0 = (w * 32) * 32;
  const int lofsA1 = (w * 32 + 16) * 32;

  f32x4 acc[4][4] = {};
  const int frow = lane & 15;
  const int fk = (lane >> 4) * 8;

  // prologue: fill buf 0
  gl_lds16(gA0, &As[0][lofsA0]);
  gl_lds16(gA1, &As[0][lofsA1]);
  gl_lds16(gB0, &Bs[0][lofsA0]);
  gl_lds16(gB1, &Bs[0][lofsA1]);
  __syncthreads();

  GEMM_DBUF_LOOP()

  const int crow = (lane >> 4) * 4;
  const int ccol = lane & 15;
  const float* brow = bias + (size_t)bz * strideBias + (size_t)bn * 128;
#pragma unroll
  for (int nt = 0; nt < 4; ++nt) {
    int col = wn * 64 + nt * 16 + ccol;
    float bv = brow[col];
#pragma unroll
    for (int mt = 0; mt < 4; ++mt) {
      f32x4 v = acc[mt][nt];
#pragma unroll
      for (int r = 0; r < 4; ++r) {
        float val = v[r] + bv;
        if (RELU) val = fmaxf(val, 0.f);
        size_t row = (size_t)bm * 128 + wm * 64 + mt * 16 + crow + r;
        size_t off = (size_t)bz * strideC + row * ldc + (size_t)bn * 128 + col;
        if (OUT_BF16) ((unsigned short*)Cv)[off] = f2bf(val);
        else          ((float*)Cv)[off] = val;
      }
    }
  }
}

// ---------- sparse bf16 MFMA GEMM over live-tile work list (compact rows) ----------
// A rows and C rows live at offs[bz] in compact buffers.
template <bool RELU>
__global__ __launch_bounds__(256) void gemm_sparse(
    const unsigned short* __restrict__ A, int lda,
    const unsigned short* __restrict__ Bt, int ldb, long long strideB,
    unsigned short* __restrict__ C, int ldc,
    const float* __restrict__ bias, int strideBias, int K,
    const int* __restrict__ counts, const int* __restrict__ offs,
    const int* __restrict__ work, const int* __restrict__ totalp,
    int lgn, int gm1, int Bc, int cap) {
  __shared__ __align__(16) unsigned short As[2][128 * 32];
  __shared__ __align__(16) unsigned short Bs[2][128 * 32];
  const int tid = threadIdx.x;
  const int w = tid >> 6, lane = tid & 63;
  const int wm = w >> 1, wn = w & 1;

  int T = (*totalp) << lgn;            // live block count
  const int nwg = gridDim.x;
  if (T > nwg) T = nwg;                // defensive
  const int j = blockIdx.x;
  const int x = j & 7, rank = j >> 3;  // x ~ XCD (dispatch round-robin)
  const int q = T >> 3, r = T & 7;
  const int quota = q + (x < r ? 1 : 0);
  if (rank >= quota) return;           // uniform early-exit (no barrier yet)
  const int i = (x < r ? x * (q + 1) : r * (q + 1) + (x - r) * q) + rank;
  const int tile = i >> lgn, bn = i & ((1 << lgn) - 1);
  const int wentry = work[tile];
  const int bz = (wentry >> 8) & 15;
  const int bm = wentry & (gm1 - 1);   // gm1 is a power of two
  int mcount = counts[bz];
  if (mcount > Bc) mcount = Bc;        // defensive clamp
  if (mcount < 0) mcount = 0;
  int offz = offs[bz];
  if (offz < 0) offz = 0;
  if (offz > cap - Bc) offz = cap - Bc;

  const unsigned short* Ab = A + (size_t)(offz + bm * 128) * lda;
  const unsigned short* Bb = Bt + (size_t)bz * strideB + (size_t)bn * 128 * ldb;

  const int srow = lane >> 2;
  const int scol = (lane & 3) * 8;
  const unsigned short* gA0 = Ab + (size_t)(w * 32 + srow) * lda + scol;
  const unsigned short* gA1 = gA0 + (size_t)16 * lda;
  const unsigned short* gB0 = Bb + (size_t)(w * 32 + srow) * ldb + scol;
  const unsigned short* gB1 = gB0 + (size_t)16 * ldb;
  const int lofsA0 = (w * 32) * 32;
  const int lofsA1 = (w * 32 + 16) * 32;

  f32x4 acc[4][4] = {};
  const int frow = lane & 15;
  const int fk = (lane >> 4) * 8;

  // prologue: fill buf 0
  gl_lds16(gA0, &As[0][lofsA0]);
  gl_lds16(gA1, &As[0][lofsA1]);
  gl_lds16(gB0, &Bs[0][lofsA0]);
  gl_lds16(gB1, &Bs[0][lofsA1]);
  __syncthreads();

  GEMM_DBUF_LOOP()

  const int crow = (lane >> 4) * 4;
  const int ccol = lane & 15;
  const float* brow = bias + (size_t)bz * strideBias + (size_t)bn * 128;
#pragma unroll
  for (int nt = 0; nt < 4; ++nt) {
    int col = wn * 64 + nt * 16 + ccol;
    float bv = brow[col];
#pragma unroll
    for (int mt = 0; mt < 4; ++mt) {
      f32x4 v = acc[mt][nt];
#pragma unroll
      for (int r = 0; r < 4; ++r) {
        float val = v[r] + bv;
        if (RELU) val = fmaxf(val, 0.f);
        int row = bm * 128 + wm * 64 + mt * 16 + crow + r;
        if (row < mcount) {
          size_t off = (size_t)(offz + row) * ldc + (size_t)bn * 128 + col;
          C[off] = f2bf(val);
        }
      }
    }
  }
}

// ---------- gate combine (compact eo via offs + slotmap) ----------
__global__ __launch_bounds__(128) void combine_kernel(
    const unsigned short* __restrict__ eo, const float* __restrict__ g,
    unsigned short* __restrict__ go, int b0, const int* __restrict__ offs,
    const int* __restrict__ slotmap, int Bc, int cap) {
  const int bl = blockIdx.x, t = blockIdx.y;
  const int b = b0 + bl;
  const int o = threadIdx.x;
  const float* grow = g + ((size_t)t * 8192 + b) * 16;
  float a0 = 0, a1 = 0, a2 = 0, a3 = 0;
  for (int e = 0; e < 16; ++e) {
    float ge = grow[e];
    if (ge != 0.f) {                      // block-uniform branch
      const int slot = slotmap[e * Bc + bl] & (Bc - 1);
      int oz = offs[e];
      if (oz < 0) oz = 0;
      if (oz > cap - Bc) oz = cap - Bc;
      const unsigned short* row = eo + (size_t)(oz + slot) * 512;
      a0 = fmaf(ge, bf2f(row[o]), a0);
      a1 = fmaf(ge, bf2f(row[o + 128]), a1);
      a2 = fmaf(ge, bf2f(row[o + 256]), a2);
      a3 = fmaf(ge, bf2f(row[o + 384]), a3);
    }
  }
  unsigned short* orow = go + ((size_t)t * 8192 + b) * 512;
  orow[o] = f2bf(a0); orow[o + 128] = f2bf(a1);
  orow[o + 256] = f2bf(a2); orow[o + 384] = f2bf(a3);
}

// ---------- final: out[t*8192+b] = dot(t2[t][b][:256], Wh3[t]) + bh3[t] ----------
__global__ __launch_bounds__(256) void final_dot(const float* __restrict__ t2,
                                                 const float* __restrict__ Wh3,
                                                 const float* __restrict__ bh3,
                                                 float* __restrict__ out) {
  const int row = blockIdx.x * 4 + (threadIdx.x >> 6);  // one wave per row
  const int lane = threadIdx.x & 63;
  const int t = row >> 13;
  const float* trow = t2 + (size_t)row * 256;
  const float* w = Wh3 + t * 256;
  float s = 0.f;
#pragma unroll
  for (int j = 0; j < 4; ++j) s = fmaf(trow[lane + j * 64], w[lane + j * 64], s);
#pragma unroll
  for (int off = 32; off > 0; off >>= 1) s += __shfl_down(s, off, 64);
  if (lane == 0) out[row] = s + bh3[t];
}

// ---------- orchestration ----------
extern "C" void kernel_launch(void* const* d_in, const int* in_sizes, int n_in,
                              void* d_out, int out_size, void* d_ws, size_t ws_size,
                              hipStream_t stream) {
  (void)in_sizes; (void)n_in; (void)out_size;
  const float* x   = (const float*)d_in[0];
  const float* We1 = (const float*)d_in[1];
  const float* be1 = (const float*)d_in[2];
  const float* We2 = (const float*)d_in[3];
  const float* be2 = (const float*)d_in[4];
  const float* Wg  = (const float*)d_in[5];
  const float* Wn  = (const float*)d_in[6];
  const float* Wh1 = (const float*)d_in[7];
  const float* bh1 = (const float*)d_in[8];
  const float* Wh2 = (const float*)d_in[9];
  const float* bh2 = (const float*)d_in[10];
  const float* Wh3 = (const float*)d_in[11];
  const float* bh3 = (const float*)d_in[12];

  auto al = [](size_t v) { return (v + 255) & ~(size_t)255; };
  const size_t sz_xb   = al((size_t)8192 * 1024 * 2);
  const size_t sz_We1t = al((size_t)16 * 1024 * 1024 * 2);
  const size_t sz_We2t = al((size_t)16 * 512 * 1024 * 2);
  const size_t sz_Wh1t = al((size_t)2 * 512 * 512 * 2);
  const size_t sz_Wh2t = al((size_t)2 * 256 * 512 * 2);
  const size_t sz_g    = al((size_t)2 * 8192 * 16 * 4);
  const size_t sz_go   = al((size_t)2 * 8192 * 512 * 2);
  const size_t sz_cnt  = al((size_t)8 * 16 * 4);
  const size_t sz_lst  = al((size_t)16 * 8192 * 4);
  const size_t sz_smp  = al((size_t)16 * 8192 * 4);
  const size_t sz_wrk  = al((size_t)1024 * 4);
  const size_t sz_tot  = al((size_t)8 * 4);
  const size_t sz_off  = al((size_t)8 * 16 * 4);
  const size_t fixed = sz_xb + sz_We1t + sz_We2t + sz_Wh1t + sz_Wh2t + sz_g +
                       sz_go + sz_cnt + sz_lst + sz_smp + sz_wrk + sz_tot + sz_off;
  const size_t sz_t1 = al((size_t)2 * 8192 * 512 * 2);   // bf16
  const size_t sz_t2 = al((size_t)2 * 8192 * 256 * 4);   // f32
  const size_t sz_t12 = sz_t1 + sz_t2;

  // Compact allocation: row capacity 8*Bc + 2048 (top-4 union over 2 tasks
  // routes each row to <= 8 experts; +16*128 padding guard). Region hosts
  // xg (aliased by eo after FC1) + h; later aliased by t1/t2.
  int Bc = 1024;
  {
    const int cands[4] = {8192, 4096, 2048, 1024};
    for (int ci = 0; ci < 4; ++ci) {
      int c = cands[ci];
      size_t cap_c = (size_t)8 * c + 2048;
      size_t region = 2 * al(cap_c * 1024 * 2);
      if (region < sz_t12) region = sz_t12;
      if (fixed + region <= ws_size) { Bc = c; break; }
    }
  }
  const int cap = 8 * Bc + 2048;
  const size_t sz_hc = al((size_t)cap * 1024 * 2);
  const int nchunk = 8192 / Bc;
  const int gm1 = Bc / 128;            // power of two

  char* ws = (char*)d_ws;
  size_t off = 0;
  auto carve = [&](size_t bytes) -> char* { char* p = ws + off; off += bytes; return p; };
  unsigned short* xb   = (unsigned short*)carve(sz_xb);
  unsigned short* We1t = (unsigned short*)carve(sz_We1t);
  unsigned short* We2t = (unsigned short*)carve(sz_We2t);
  unsigned short* Wh1t = (unsigned short*)carve(sz_Wh1t);
  unsigned short* Wh2t = (unsigned short*)carve(sz_Wh2t);
  float* g             = (float*)carve(sz_g);
  unsigned short* go   = (unsigned short*)carve(sz_go);
  int* counts          = (int*)carve(sz_cnt);
  int* lists           = (int*)carve(sz_lst);
  int* slotmap         = (int*)carve(sz_smp);
  int* work            = (int*)carve(sz_wrk);
  int* totals          = (int*)carve(sz_tot);
  int* offsets         = (int*)carve(sz_off);
  char* region         = ws + off;
  unsigned short* xg   = (unsigned short*)region;            // [cap][1024] compacted x
  unsigned short* eo   = (unsigned short*)region;            // [cap][512] (aliases xg)
  unsigned short* h    = (unsigned short*)(region + sz_hc);  // [cap][1024] compacted
  unsigned short* t1   = (unsigned short*)region;            // aliases (dead by towers)
  float* t2            = (float*)(region + sz_t1);

  // prep: casts + weight transposes (B operands need N x K)
  cvt_x<<<8192, 256, 0, stream>>>(x, xb);
  transpose_bf16<<<dim3(32, 32, 16), 256, 0, stream>>>(We1, We1t, 1024, 1024);
  transpose_bf16<<<dim3(16, 32, 16), 256, 0, stream>>>(We2, We2t, 1024, 512);
  transpose_bf16<<<dim3(16, 16, 2), 256, 0, stream>>>(Wh1, Wh1t, 512, 512);
  transpose_bf16<<<dim3(8, 16, 2), 256, 0, stream>>>(Wh2, Wh2t, 512, 256);

  // gating (fp32, threefry noise, top-4 softmax)
  gating_kernel<<<1024, 256, 0, stream>>>(x, Wg, Wn, g);
  // routing metadata
  zero_counts<<<1, 256, 0, stream>>>(counts, nchunk * 16);
  build_lists<<<32, 256, 0, stream>>>(g, Bc, counts, lists, slotmap);
  build_work<<<nchunk, 64, 0, stream>>>(counts, work, totals, offsets, gm1, Bc, cap);

  // expert pipeline, chunked over batch; only routed tiles are computed
  for (int b0 = 0; b0 < 8192; b0 += Bc) {
    const int chunk = b0 / Bc;
    const int* cnt = counts + chunk * 16;
    const int* lst = lists + (size_t)chunk * 16 * Bc;
    const int* smp = slotmap + (size_t)chunk * 16 * Bc;
    const int* wrk = work + chunk * gm1 * 16;
    const int* tot = totals + chunk;
    const int* ofs = offsets + chunk * 16;
    // compact routed x rows (streaming gather; latency hidden by TLP)
    gather_rows<<<dim3(Bc / 4, 16), 256, 0, stream>>>(xb, cnt, lst, ofs, xg, Bc, cap);
    // FC1 (sparse): h[offs[e]+slot][:] = relu(xg[offs[e]+slot] @ We1[e] + be1[e]); gn=8
    gemm_sparse<true><<<gm1 * 16 * 8, 256, 0, stream>>>(
        xg, 1024,
        We1t, 1024, (long long)1024 * 1024,
        h, 1024, be1, 1024, 1024,
        cnt, ofs, wrk, tot, 3, gm1, Bc, cap);
    // FC2 (sparse): eo[offs[e]+slot][:] = h[offs[e]+slot] @ We2[e] + be2[e]; gn=4
    // (eo aliases xg, dead after FC1)
    gemm_sparse<false><<<gm1 * 16 * 4, 256, 0, stream>>>(
        h, 1024,
        We2t, 1024, (long long)512 * 1024,
        eo, 512, be2, 512, 1024,
        cnt, ofs, wrk, tot, 2, gm1, Bc, cap);
    // combine into go rows [b0, b0+Bc) via offs + slotmap
    combine_kernel<<<dim3(Bc, 2), 128, 0, stream>>>(
        eo, g, go, b0, ofs, smp, Bc, cap);
  }

  // towers (full batch, dense + XCD swizzle)
  gemm_bt<true, true><<<64 * 4 * 2, 256, 0, stream>>>(
      go, 512, (long long)8192 * 512, Wh1t, 512, (long long)512 * 512,
      t1, 512, (long long)8192 * 512, bh1, 512, 512,
      64, 4);
  gemm_bt<true, false><<<64 * 2 * 2, 256, 0, stream>>>(
      t1, 512, (long long)8192 * 512, Wh2t, 512, (long long)256 * 512,
      t2, 256, (long long)8192 * 256, bh2, 256, 512,
      64, 2);

  final_dot<<<4096, 256, 0, stream>>>(t2, Wh3, bh3, (float*)d_out);
}

// Round 11
// 620.988 us; speedup vs baseline: 1.2480x; 1.1308x over previous
//
#include <hip/hip_runtime.h>

#define AS1 __attribute__((address_space(1)))
#define AS3 __attribute__((address_space(3)))

typedef __bf16 bf16x8 __attribute__((ext_vector_type(8)));
typedef float f32x4 __attribute__((ext_vector_type(4)));

// ---------- small helpers ----------
__device__ __forceinline__ unsigned short f2bf(float f) {
  unsigned u = __float_as_uint(f);
  u += 0x7FFFu + ((u >> 16) & 1u);   // RNE
  return (unsigned short)(u >> 16);
}
__device__ __forceinline__ float bf2f(unsigned short u) {
  return __uint_as_float(((unsigned)u) << 16);
}

__device__ __forceinline__ void gl_lds16(const void* g, void* l) {
  // async global->LDS, 16B per lane; LDS dest = wave-uniform base + lane*16
  __builtin_amdgcn_global_load_lds((const AS1 unsigned int*)g,
                                   (AS3 unsigned int*)l, 16, 0, 0);
}

// ---------- Threefry-2x32 (20 rounds), JAX-compatible ----------
__device__ __forceinline__ unsigned rotl32(unsigned v, int s) {
  return (v << s) | (v >> (32 - s));
}
__device__ __forceinline__ void threefry2x32(unsigned k0, unsigned k1,
                                             unsigned x0, unsigned x1,
                                             unsigned& o0, unsigned& o1) {
  const unsigned ks2 = k0 ^ k1 ^ 0x1BD11BDAu;
  x0 += k0; x1 += k1;
  x0 += x1; x1 = rotl32(x1, 13); x1 ^= x0;
  x0 += x1; x1 = rotl32(x1, 15); x1 ^= x0;
  x0 += x1; x1 = rotl32(x1, 26); x1 ^= x0;
  x0 += x1; x1 = rotl32(x1, 6);  x1 ^= x0;
  x0 += k1; x1 += ks2 + 1u;
  x0 += x1; x1 = rotl32(x1, 17); x1 ^= x0;
  x0 += x1; x1 = rotl32(x1, 29); x1 ^= x0;
  x0 += x1; x1 = rotl32(x1, 16); x1 ^= x0;
  x0 += x1; x1 = rotl32(x1, 24); x1 ^= x0;
  x0 += ks2; x1 += k0 + 2u;
  x0 += x1; x1 = rotl32(x1, 13); x1 ^= x0;
  x0 += x1; x1 = rotl32(x1, 15); x1 ^= x0;
  x0 += x1; x1 = rotl32(x1, 26); x1 ^= x0;
  x0 += x1; x1 = rotl32(x1, 6);  x1 ^= x0;
  x0 += k0; x1 += k1 + 3u;
  x0 += x1; x1 = rotl32(x1, 17); x1 ^= x0;
  x0 += x1; x1 = rotl32(x1, 29); x1 ^= x0;
  x0 += x1; x1 = rotl32(x1, 16); x1 ^= x0;
  x0 += x1; x1 = rotl32(x1, 24); x1 ^= x0;
  x0 += k1; x1 += ks2 + 4u;
  x0 += x1; x1 = rotl32(x1, 13); x1 ^= x0;
  x0 += x1; x1 = rotl32(x1, 15); x1 ^= x0;
  x0 += x1; x1 = rotl32(x1, 26); x1 ^= x0;
  x0 += x1; x1 = rotl32(x1, 6);  x1 ^= x0;
  o0 = x0 + ks2; o1 = x1 + k0 + 5u;
}

// XLA f32 erf_inv (Giles polynomial)
__device__ __forceinline__ float erfinv32(float x) {
  float w = -log1pf(-x * x);
  float p;
  if (w < 5.f) {
    w = w - 2.5f;
    p = 2.81022636e-08f;
    p = fmaf(p, w, 3.43273939e-07f);
    p = fmaf(p, w, -3.5233877e-06f);
    p = fmaf(p, w, -4.39150654e-06f);
    p = fmaf(p, w, 0.00021858087f);
    p = fmaf(p, w, -0.00125372503f);
    p = fmaf(p, w, -0.00417768164f);
    p = fmaf(p, w, 0.246640727f);
    p = fmaf(p, w, 1.50140941f);
  } else {
    w = sqrtf(w) - 3.f;
    p = -0.000200214257f;
    p = fmaf(p, w, 0.000100950558f);
    p = fmaf(p, w, 0.00134934322f);
    p = fmaf(p, w, -0.00367342844f);
    p = fmaf(p, w, 0.00573950773f);
    p = fmaf(p, w, -0.0076224613f);
    p = fmaf(p, w, 0.00943887047f);
    p = fmaf(p, w, 1.00167406f);
    p = fmaf(p, w, 2.83297682f);
  }
  return p * x;
}

// bits -> N(0,1) exactly as jax.random.normal (f32)
__device__ __forceinline__ float bits_to_normal(unsigned bits) {
  float f = __uint_as_float((bits >> 9) | 0x3f800000u) - 1.0f;  // [0,1)
  const float lo = -0.99999994f;       // nextafter(-1,0)
  float u = fmaf(f, 2.0f, lo);
  u = fmaxf(u, lo);
  return 1.41421356f * erfinv32(u);
}

// ---------- conversion / transpose kernels ----------
__global__ __launch_bounds__(256) void cvt_x(const float* __restrict__ in,
                                             unsigned short* __restrict__ out) {
  const int i = blockIdx.x * 256 + threadIdx.x;
  const float4 v = ((const float4*)in)[i];
  ushort4 o;
  o.x = f2bf(v.x); o.y = f2bf(v.y); o.z = f2bf(v.z); o.w = f2bf(v.w);
  ((ushort4*)out)[i] = o;
}

// in: [batch][R][C] f32  ->  out: [batch][C][R] bf16
__global__ __launch_bounds__(256) void transpose_bf16(
    const float* __restrict__ in, unsigned short* __restrict__ out, int R, int C) {
  __shared__ float tile[32][33];
  const int bz = blockIdx.z;
  in  += (size_t)bz * R * C;
  out += (size_t)bz * R * C;
  const int c0 = blockIdx.x * 32, r0 = blockIdx.y * 32;
  const int tx = threadIdx.x & 31, ty = threadIdx.x >> 5;  // 32x8
#pragma unroll
  for (int i = 0; i < 32; i += 8)
    tile[ty + i][tx] = in[(size_t)(r0 + ty + i) * C + c0 + tx];
  __syncthreads();
#pragma unroll
  for (int i = 0; i < 32; i += 8)
    out[(size_t)(c0 + ty + i) * R + r0 + tx] = f2bf(tile[tx][ty + i]);
}

// ---------- gating: mean/std/noise/top-k/softmax, all fp32 ----------
__global__ __launch_bounds__(256) void gating_kernel(
    const float* __restrict__ x, const float* __restrict__ Wg,
    const float* __restrict__ Wn, float* __restrict__ g) {
  __shared__ float xs[8][1024];
  __shared__ float partial[64][4][8];
  __shared__ float meanS[2][8][16];
  __shared__ float stdS[2][8][16];
  __shared__ float noisyS[2][8][16];
  const int tid = threadIdx.x;
  const int b0 = blockIdx.x * 8;
  for (int idx = tid; idx < 8 * 1024; idx += 256) {
    int r = idx >> 10, c = idx & 1023;
    xs[r][c] = x[(size_t)(b0 + r) * 1024 + c];
  }
  __syncthreads();
  {
    const int c = tid & 63;          // column id: t*32 + which*16 + e
    const int q = tid >> 6;          // K-partition 0..3
    const int t = c >> 5, which = (c >> 4) & 1, e = c & 15;
    const float* Wcol = (which ? Wn : Wg) + (size_t)t * 1024 * 16 + e;
    float acc[8] = {0, 0, 0, 0, 0, 0, 0, 0};
    const int i0 = q * 256;
    for (int i = i0; i < i0 + 256; ++i) {
      float w = Wcol[(size_t)i * 16];
#pragma unroll
      for (int r = 0; r < 8; ++r) acc[r] = fmaf(w, xs[r][i], acc[r]);
    }
#pragma unroll
    for (int r = 0; r < 8; ++r) partial[c][q][r] = acc[r];
  }
  __syncthreads();
  for (int idx = tid; idx < 512; idx += 256) {
    int c = idx >> 3, r = idx & 7;
    float s = partial[c][0][r] + partial[c][1][r] + partial[c][2][r] + partial[c][3][r];
    int t = c >> 5, which = (c >> 4) & 1, e = c & 15;
    if (which)  // softplus
      stdS[t][r][e] = fmaxf(s, 0.f) + log1pf(expf(-fabsf(s)));
    else
      meanS[t][r][e] = s;
  }
  __syncthreads();
  if (tid < 128) {
    int r = tid >> 4, e = tid & 15;
    unsigned p = (unsigned)((b0 + r) * 16 + e);
#pragma unroll
    for (int t = 0; t < 2; ++t) {
      unsigned n = (unsigned)t * 131072u + p;  // flat index into (T,B,E)
      unsigned y0, y1;
      threefry2x32(0u, 42u, 0u, n, y0, y1);    // partitionable: counter=(0, n)
      float nrm = bits_to_normal(y0 ^ y1);
      noisyS[t][r][e] = meanS[t][r][e] + nrm * stdS[t][r][e];
    }
  }
  __syncthreads();
  if (tid < 16) {
    int r = tid >> 1, t = tid & 1;
    float v[16];
#pragma unroll
    for (int e = 0; e < 16; ++e) v[e] = noisyS[t][r][e];
    float m0 = -1e30f, m1 = -1e30f, m2 = -1e30f, m3 = -1e30f;
#pragma unroll
    for (int e = 0; e < 16; ++e) {
      float val = v[e];
      if (val > m0) { m3 = m2; m2 = m1; m1 = m0; m0 = val; }
      else if (val > m1) { m3 = m2; m2 = m1; m1 = val; }
      else if (val > m2) { m3 = m2; m2 = val; }
      else if (val > m3) { m3 = val; }
    }
    float sum = 0.f, ge[16];
#pragma unroll
    for (int e = 0; e < 16; ++e) {
      if (v[e] >= m3) { ge[e] = expf(v[e] - m0); sum += ge[e]; }
      else ge[e] = 0.f;
    }
    float inv = 1.f / sum;
    float* grow = g + ((size_t)t * 8192 + (b0 + r)) * 16;
#pragma unroll
    for (int e = 0; e < 16; ++e) grow[e] = ge[e] * inv;
  }
}

// ---------- MoE dispatch metadata ----------
__global__ __launch_bounds__(256) void zero_counts(int* __restrict__ counts,
                                                   int n) {
  const int i = blockIdx.x * 256 + threadIdx.x;
  if (i < n) counts[i] = 0;
}

// per-(chunk,expert) row lists from g's exact-zero sparsity
// wave-aggregated: one atomic per (wave, expert) instead of per (row, expert)
__global__ __launch_bounds__(256) void build_lists(
    const float* __restrict__ g, int Bc, int* __restrict__ counts,
    int* __restrict__ lists, int* __restrict__ slotmap) {
  const int b = blockIdx.x * 256 + threadIdx.x;  // 8192 threads total
  const int lane = threadIdx.x & 63;
  const int chunk = b / Bc, bl = b % Bc;         // chunk is wave-uniform (Bc>=1024)
  float v0[16], v1[16];
  {
    const float4* p0 = (const float4*)(g + (size_t)b * 16);
    const float4* p1 = (const float4*)(g + ((size_t)8192 + b) * 16);
#pragma unroll
    for (int i = 0; i < 4; ++i) {
      ((float4*)v0)[i] = p0[i];
      ((float4*)v1)[i] = p1[i];
    }
  }
  int* cnt = counts + chunk * 16;
  int* lst = lists + (size_t)chunk * 16 * Bc;
  int* smp = slotmap + (size_t)chunk * 16 * Bc;
#pragma unroll
  for (int e = 0; e < 16; ++e) {
    const bool want = (v0[e] != 0.f) || (v1[e] != 0.f);
    const unsigned long long mask = __ballot(want);
    int base = 0;
    if (lane == 0) base = atomicAdd(&cnt[e], (int)__popcll(mask));
    base = __shfl(base, 0, 64);
    if (want) {
      const int slot = base + (int)__popcll(mask & ((1ULL << lane) - 1ULL));
      if (slot < Bc) {                 // defensive: never write OOB
        lst[e * Bc + slot] = b;        // global row index into x
        smp[e * Bc + bl] = slot;       // inverse map for combine
      }
    }
  }
}

// flatten live (e,bm) tiles expert-major into work[] + padded per-expert
// row offsets (compact allocation: capacity cap = 8*Bc + 2048 rows).
__global__ __launch_bounds__(64) void build_work(
    const int* __restrict__ counts, int* __restrict__ work,
    int* __restrict__ totals, int* __restrict__ offsets,
    int gm1, int Bc, int cap) {
  const int chunk = blockIdx.x;
  if (threadIdx.x != 0) return;
  const int* cnt = counts + chunk * 16;
  int* w = work + chunk * gm1 * 16;
  int* offs = offsets + chunk * 16;
  int s = 0;      // tile index
  int rows = 0;   // padded row offset
  for (int e = 0; e < 16; ++e) {
    int c = cnt[e];
    if (c < 0) c = 0;
    if (c > Bc) c = Bc;
    int o = rows;
    if (o > cap - Bc) o = cap - Bc;   // defensive: expert writes <= Bc rows
    offs[e] = o;
    const int nt = (c + 127) >> 7;
    for (int t = 0; t < nt; ++t) w[s + t] = (e << 8) | t;
    s += nt;
    rows += nt << 7;                  // pad to 128 rows
  }
  totals[chunk] = s;
}

// ---------- row compaction: xg[offs[e]+slot][:] = xb[lists[e][slot]][:] ----------
__global__ __launch_bounds__(256) void gather_rows(
    const unsigned short* __restrict__ xb, const int* __restrict__ counts,
    const int* __restrict__ lists, const int* __restrict__ offs,
    unsigned short* __restrict__ xg, int Bc, int cap) {
  const int e = blockIdx.y;
  const int slot = blockIdx.x * 4 + (threadIdx.x >> 6);
  const int lane = threadIdx.x & 63;
  int c = counts[e];
  if (c > Bc) c = Bc;
  if (slot >= c) return;
  int o = offs[e];
  if (o < 0) o = 0;
  if (o > cap - Bc) o = cap - Bc;
  const int r = lists[(size_t)e * Bc + slot] & 8191;
  const float4* src = (const float4*)(xb + (size_t)r * 1024);
  float4* dst = (float4*)(xg + ((size_t)o + slot) * 1024);
  dst[lane] = src[lane];
  dst[lane + 64] = src[lane + 64];
}

// ---------- shared double-buffered K-loop (2-phase; r7-proven) ----------
// stage next K-tile into buf[1-c] BEFORE computing buf[c]; one barrier/K-step.
// ASB/BSB are ushort* bases; buffer i at +i*4096.
#define GEMM_DBUF_LOOP(ASB, BSB)                                              \
  for (int k0 = 0; k0 < K; k0 += 32) {                                        \
    const int cur = (k0 >> 5) & 1;                                            \
    if (k0 + 32 < K) {                                                        \
      const int nxt = cur ^ 1;                                                \
      gl_lds16(gA0 + k0 + 32, &(ASB)[nxt * 4096 + lofsA0]);                   \
      gl_lds16(gA1 + k0 + 32, &(ASB)[nxt * 4096 + lofsA1]);                   \
      gl_lds16(gB0 + k0 + 32, &(BSB)[nxt * 4096 + lofsA0]);                   \
      gl_lds16(gB1 + k0 + 32, &(BSB)[nxt * 4096 + lofsA1]);                   \
    }                                                                         \
    bf16x8 af[4], bfr[4];                                                     \
    _Pragma("unroll")                                                         \
    for (int mt = 0; mt < 4; ++mt)                                            \
      af[mt] = *(const bf16x8*)&(ASB)[cur * 4096 +                            \
                                      (wm * 64 + mt * 16 + frow) * 32 + fk];  \
    _Pragma("unroll")                                                         \
    for (int nt = 0; nt < 4; ++nt)                                            \
      bfr[nt] = *(const bf16x8*)&(BSB)[cur * 4096 +                           \
                                       (wn * 64 + nt * 16 + frow) * 32 + fk]; \
    _Pragma("unroll")                                                         \
    for (int mt = 0; mt < 4; ++mt)                                            \
      _Pragma("unroll")                                                       \
      for (int nt = 0; nt < 4; ++nt)                                          \
        acc[mt][nt] = __builtin_amdgcn_mfma_f32_16x16x32_bf16(                \
            af[mt], bfr[nt], acc[mt][nt], 0, 0, 0);                           \
    __syncthreads();                                                          \
  }

#define GEMM_DBUF_PROLOGUE(ASB, BSB)                                          \
  gl_lds16(gA0, &(ASB)[lofsA0]);                                              \
  gl_lds16(gA1, &(ASB)[lofsA1]);                                              \
  gl_lds16(gB0, &(BSB)[lofsA0]);                                              \
  gl_lds16(gB1, &(BSB)[lofsA1]);                                              \
  __syncthreads();

// ---------- dense bf16 MFMA GEMM with XCD chunked swizzle (towers) ----------
template <bool RELU, bool OUT_BF16>
__global__ __launch_bounds__(256) void gemm_bt(
    const unsigned short* __restrict__ A, int lda, long long strideA,
    const unsigned short* __restrict__ Bt, int ldb, long long strideB,
    void* __restrict__ Cv, int ldc, long long strideC,
    const float* __restrict__ bias, int strideBias, int K,
    int gm, int gn) {
  __shared__ __align__(16) unsigned short As[2 * 4096];
  __shared__ __align__(16) unsigned short Bs[2 * 4096];
  const int tid = threadIdx.x;
  const int w = tid >> 6, lane = tid & 63;
  const int wm = w >> 1, wn = w & 1;

  int swz = blockIdx.x;
  const int nwg = gridDim.x;
  if ((nwg & 7) == 0) swz = (swz & 7) * (nwg >> 3) + (swz >> 3);
  const int bm = swz % gm;
  const int tmp = swz / gm;
  const int bn = tmp % gn;
  const int bz = tmp / gn;

  const unsigned short* Ab = A + (size_t)bz * strideA + (size_t)bm * 128 * lda;
  const unsigned short* Bb = Bt + (size_t)bz * strideB + (size_t)bn * 128 * ldb;

  const int srow = lane >> 2;
  const int scol = (lane & 3) * 8;
  const unsigned short* gA0 = Ab + (size_t)(w * 32 + srow) * lda + scol;
  const unsigned short* gA1 = gA0 + (size_t)16 * lda;
  const unsigned short* gB0 = Bb + (size_t)(w * 32 + srow) * ldb + scol;
  const unsigned short* gB1 = gB0 + (size_t)16 * ldb;
  const int lofsA0 = (w * 32) * 32;
  const int lofsA1 = (w * 32 + 16) * 32;

  f32x4 acc[4][4] = {};
  const int frow = lane & 15;
  const int fk = (lane >> 4) * 8;

  GEMM_DBUF_PROLOGUE(As, Bs)
  GEMM_DBUF_LOOP(As, Bs)

  const int crow = (lane >> 4) * 4;
  const int ccol = lane & 15;
  const float* brow = bias + (size_t)bz * strideBias + (size_t)bn * 128;
#pragma unroll
  for (int nt = 0; nt < 4; ++nt) {
    int col = wn * 64 + nt * 16 + ccol;
    float bv = brow[col];
#pragma unroll
    for (int mt = 0; mt < 4; ++mt) {
      f32x4 v = acc[mt][nt];
#pragma unroll
      for (int r = 0; r < 4; ++r) {
        float val = v[r] + bv;
        if (RELU) val = fmaxf(val, 0.f);
        size_t row = (size_t)bm * 128 + wm * 64 + mt * 16 + crow + r;
        size_t off = (size_t)bz * strideC + row * ldc + (size_t)bn * 128 + col;
        if (OUT_BF16) ((unsigned short*)Cv)[off] = f2bf(val);
        else          ((float*)Cv)[off] = val;
      }
    }
  }
}

// ---------- sparse bf16 MFMA GEMM over live-tile work list (compact rows) ----------
// A rows and C rows live at offs[bz] in compact buffers.
// Epilogue: LDS-staged coalesced C-write (16B/lane full-line stores) to fix
// the 2x WRITE_SIZE amplification of the scattered 2B store pattern.
template <bool RELU>
__global__ __launch_bounds__(256) void gemm_sparse(
    const unsigned short* __restrict__ A, int lda,
    const unsigned short* __restrict__ Bt, int ldb, long long strideB,
    unsigned short* __restrict__ C, int ldc,
    const float* __restrict__ bias, int strideBias, int K,
    const int* __restrict__ counts, const int* __restrict__ offs,
    const int* __restrict__ work, const int* __restrict__ totalp,
    int lgn, int gm1, int Bc, int cap) {
  // 32KB: As|Bs during K-loop; reused as 128x128 bf16 C-stage in epilogue
  __shared__ __align__(16) unsigned short smem[16384];
  unsigned short* AsP = smem;          // [2][4096]
  unsigned short* BsP = smem + 8192;   // [2][4096]
  const int tid = threadIdx.x;
  const int w = tid >> 6, lane = tid & 63;
  const int wm = w >> 1, wn = w & 1;

  int T = (*totalp) << lgn;            // live block count
  const int nwg = gridDim.x;
  if (T > nwg) T = nwg;                // defensive
  const int j = blockIdx.x;
  const int x = j & 7, rank = j >> 3;  // x ~ XCD (dispatch round-robin)
  const int q = T >> 3, r = T & 7;
  const int quota = q + (x < r ? 1 : 0);
  if (rank >= quota) return;           // uniform early-exit (no barrier yet)
  const int i = (x < r ? x * (q + 1) : r * (q + 1) + (x - r) * q) + rank;
  const int tile = i >> lgn, bn = i & ((1 << lgn) - 1);
  const int wentry = work[tile];
  const int bz = (wentry >> 8) & 15;
  const int bm = wentry & (gm1 - 1);   // gm1 is a power of two
  int mcount = counts[bz];
  if (mcount > Bc) mcount = Bc;        // defensive clamp
  if (mcount < 0) mcount = 0;
  int offz = offs[bz];
  if (offz < 0) offz = 0;
  if (offz > cap - Bc) offz = cap - Bc;

  const unsigned short* Ab = A + (size_t)(offz + bm * 128) * lda;
  const unsigned short* Bb = Bt + (size_t)bz * strideB + (size_t)bn * 128 * ldb;

  const int srow = lane >> 2;
  const int scol = (lane & 3) * 8;
  const unsigned short* gA0 = Ab + (size_t)(w * 32 + srow) * lda + scol;
  const unsigned short* gA1 = gA0 + (size_t)16 * lda;
  const unsigned short* gB0 = Bb + (size_t)(w * 32 + srow) * ldb + scol;
  const unsigned short* gB1 = gB0 + (size_t)16 * ldb;
  const int lofsA0 = (w * 32) * 32;
  const int lofsA1 = (w * 32 + 16) * 32;

  f32x4 acc[4][4] = {};
  const int frow = lane & 15;
  const int fk = (lane >> 4) * 8;

  GEMM_DBUF_PROLOGUE(AsP, BsP)
  GEMM_DBUF_LOOP(AsP, BsP)
  // last iteration ended with __syncthreads(): all waves' LDS reads done;
  // smem is reusable as the C-stage.

  {
    const int crow = (lane >> 4) * 4;
    const int ccol = lane & 15;
    const float* brow = bias + (size_t)bz * strideBias + (size_t)bn * 128;
#pragma unroll
    for (int nt = 0; nt < 4; ++nt) {
      int col = wn * 64 + nt * 16 + ccol;
      float bv = brow[col];
#pragma unroll
      for (int mt = 0; mt < 4; ++mt) {
        f32x4 v = acc[mt][nt];
#pragma unroll
        for (int r = 0; r < 4; ++r) {
          float val = v[r] + bv;
          if (RELU) val = fmaxf(val, 0.f);
          const int row = wm * 64 + mt * 16 + crow + r;
          // bank-XOR: the 4 row-groups of each store land on disjoint 8-bank sets
          unsigned byte = (unsigned)(row * 256 + col * 2);
          byte ^= (((unsigned)(row >> 2) & 3u) << 5);
          *(unsigned short*)((char*)smem + byte) = f2bf(val);
        }
      }
    }
    __syncthreads();
    // readback: 8 passes x (256 threads x 16B) = 32KB, full-line coalesced
#pragma unroll
    for (int p = 0; p < 8; ++p) {
      const int lb = p * 4096 + tid * 16;
      const int row = lb >> 8;          // 0..127 (wave-uniform XOR: rows/4 equal)
      const unsigned src = (unsigned)lb ^ (((unsigned)(row >> 2) & 3u) << 5);
      if (bm * 128 + row < mcount) {
        const uint4 d = *(const uint4*)((const char*)smem + src);
        *(uint4*)&C[(size_t)(offz + bm * 128 + row) * ldc + bn * 128 +
                    ((lb & 255) >> 1)] = d;
      }
    }
  }
}

// ---------- gate combine (compact eo via offs + slotmap) ----------
__global__ __launch_bounds__(128) void combine_kernel(
    const unsigned short* __restrict__ eo, const float* __restrict__ g,
    unsigned short* __restrict__ go, int b0, const int* __restrict__ offs,
    const int* __restrict__ slotmap, int Bc, int cap) {
  const int bl = blockIdx.x, t = blockIdx.y;
  const int b = b0 + bl;
  const int o = threadIdx.x;
  const float* grow = g + ((size_t)t * 8192 + b) * 16;
  float a0 = 0, a1 = 0, a2 = 0, a3 = 0;
  for (int e = 0; e < 16; ++e) {
    float ge = grow[e];
    if (ge != 0.f) {                      // block-uniform branch
      const int slot = slotmap[e * Bc + bl] & (Bc - 1);
      int oz = offs[e];
      if (oz < 0) oz = 0;
      if (oz > cap - Bc) oz = cap - Bc;
      const unsigned short* row = eo + (size_t)(oz + slot) * 512;
      a0 = fmaf(ge, bf2f(row[o]), a0);
      a1 = fmaf(ge, bf2f(row[o + 128]), a1);
      a2 = fmaf(ge, bf2f(row[o + 256]), a2);
      a3 = fmaf(ge, bf2f(row[o + 384]), a3);
    }
  }
  unsigned short* orow = go + ((size_t)t * 8192 + b) * 512;
  orow[o] = f2bf(a0); orow[o + 128] = f2bf(a1);
  orow[o + 256] = f2bf(a2); orow[o + 384] = f2bf(a3);
}

// ---------- final: out[t*8192+b] = dot(t2[t][b][:256], Wh3[t]) + bh3[t] ----------
__global__ __launch_bounds__(256) void final_dot(const float* __restrict__ t2,
                                                 const float* __restrict__ Wh3,
                                                 const float* __restrict__ bh3,
                                                 float* __restrict__ out) {
  const int row = blockIdx.x * 4 + (threadIdx.x >> 6);  // one wave per row
  const int lane = threadIdx.x & 63;
  const int t = row >> 13;
  const float* trow = t2 + (size_t)row * 256;
  const float* w = Wh3 + t * 256;
  float s = 0.f;
#pragma unroll
  for (int j = 0; j < 4; ++j) s = fmaf(trow[lane + j * 64], w[lane + j * 64], s);
#pragma unroll
  for (int off = 32; off > 0; off >>= 1) s += __shfl_down(s, off, 64);
  if (lane == 0) out[row] = s + bh3[t];
}

// ---------- orchestration ----------
extern "C" void kernel_launch(void* const* d_in, const int* in_sizes, int n_in,
                              void* d_out, int out_size, void* d_ws, size_t ws_size,
                              hipStream_t stream) {
  (void)in_sizes; (void)n_in; (void)out_size;
  const float* x   = (const float*)d_in[0];
  const float* We1 = (const float*)d_in[1];
  const float* be1 = (const float*)d_in[2];
  const float* We2 = (const float*)d_in[3];
  const float* be2 = (const float*)d_in[4];
  const float* Wg  = (const float*)d_in[5];
  const float* Wn  = (const float*)d_in[6];
  const float* Wh1 = (const float*)d_in[7];
  const float* bh1 = (const float*)d_in[8];
  const float* Wh2 = (const float*)d_in[9];
  const float* bh2 = (const float*)d_in[10];
  const float* Wh3 = (const float*)d_in[11];
  const float* bh3 = (const float*)d_in[12];

  auto al = [](size_t v) { return (v + 255) & ~(size_t)255; };
  const size_t sz_xb   = al((size_t)8192 * 1024 * 2);
  const size_t sz_We1t = al((size_t)16 * 1024 * 1024 * 2);
  const size_t sz_We2t = al((size_t)16 * 512 * 1024 * 2);
  const size_t sz_Wh1t = al((size_t)2 * 512 * 512 * 2);
  const size_t sz_Wh2t = al((size_t)2 * 256 * 512 * 2);
  const size_t sz_g    = al((size_t)2 * 8192 * 16 * 4);
  const size_t sz_go   = al((size_t)2 * 8192 * 512 * 2);
  const size_t sz_cnt  = al((size_t)8 * 16 * 4);
  const size_t sz_lst  = al((size_t)16 * 8192 * 4);
  const size_t sz_smp  = al((size_t)16 * 8192 * 4);
  const size_t sz_wrk  = al((size_t)1024 * 4);
  const size_t sz_tot  = al((size_t)8 * 4);
  const size_t sz_off  = al((size_t)8 * 16 * 4);
  const size_t fixed = sz_xb + sz_We1t + sz_We2t + sz_Wh1t + sz_Wh2t + sz_g +
                       sz_go + sz_cnt + sz_lst + sz_smp + sz_wrk + sz_tot + sz_off;
  const size_t sz_t1 = al((size_t)2 * 8192 * 512 * 2);   // bf16
  const size_t sz_t2 = al((size_t)2 * 8192 * 256 * 4);   // f32
  const size_t sz_t12 = sz_t1 + sz_t2;

  // Compact allocation: row capacity 8*Bc + 2048 (top-4 union over 2 tasks
  // routes each row to <= 8 experts; +16*128 padding guard). Region hosts
  // xg (aliased by eo after FC1) + h; later aliased by t1/t2.
  int Bc = 1024;
  {
    const int cands[4] = {8192, 4096, 2048, 1024};
    for (int ci = 0; ci < 4; ++ci) {
      int c = cands[ci];
      size_t cap_c = (size_t)8 * c + 2048;
      size_t region = 2 * al(cap_c * 1024 * 2);
      if (region < sz_t12) region = sz_t12;
      if (fixed + region <= ws_size) { Bc = c; break; }
    }
  }
  const int cap = 8 * Bc + 2048;
  const size_t sz_hc = al((size_t)cap * 1024 * 2);
  const int nchunk = 8192 / Bc;
  const int gm1 = Bc / 128;            // power of two

  char* ws = (char*)d_ws;
  size_t off = 0;
  auto carve = [&](size_t bytes) -> char* { char* p = ws + off; off += bytes; return p; };
  unsigned short* xb   = (unsigned short*)carve(sz_xb);
  unsigned short* We1t = (unsigned short*)carve(sz_We1t);
  unsigned short* We2t = (unsigned short*)carve(sz_We2t);
  unsigned short* Wh1t = (unsigned short*)carve(sz_Wh1t);
  unsigned short* Wh2t = (unsigned short*)carve(sz_Wh2t);
  float* g             = (float*)carve(sz_g);
  unsigned short* go   = (unsigned short*)carve(sz_go);
  int* counts          = (int*)carve(sz_cnt);
  int* lists           = (int*)carve(sz_lst);
  int* slotmap         = (int*)carve(sz_smp);
  int* work            = (int*)carve(sz_wrk);
  int* totals          = (int*)carve(sz_tot);
  int* offsets         = (int*)carve(sz_off);
  char* region         = ws + off;
  unsigned short* xg   = (unsigned short*)region;            // [cap][1024] compacted x
  unsigned short* eo   = (unsigned short*)region;            // [cap][512] (aliases xg)
  unsigned short* h    = (unsigned short*)(region + sz_hc);  // [cap][1024] compacted
  unsigned short* t1   = (unsigned short*)region;            // aliases (dead by towers)
  float* t2            = (float*)(region + sz_t1);

  // prep: casts + weight transposes (B operands need N x K)
  cvt_x<<<8192, 256, 0, stream>>>(x, xb);
  transpose_bf16<<<dim3(32, 32, 16), 256, 0, stream>>>(We1, We1t, 1024, 1024);
  transpose_bf16<<<dim3(16, 32, 16), 256, 0, stream>>>(We2, We2t, 1024, 512);
  transpose_bf16<<<dim3(16, 16, 2), 256, 0, stream>>>(Wh1, Wh1t, 512, 512);
  transpose_bf16<<<dim3(8, 16, 2), 256, 0, stream>>>(Wh2, Wh2t, 512, 256);

  // gating (fp32, threefry noise, top-4 softmax)
  gating_kernel<<<1024, 256, 0, stream>>>(x, Wg, Wn, g);
  // routing metadata
  zero_counts<<<1, 256, 0, stream>>>(counts, nchunk * 16);
  build_lists<<<32, 256, 0, stream>>>(g, Bc, counts, lists, slotmap);
  build_work<<<nchunk, 64, 0, stream>>>(counts, work, totals, offsets, gm1, Bc, cap);

  // expert pipeline, chunked over batch; only routed tiles are computed
  for (int b0 = 0; b0 < 8192; b0 += Bc) {
    const int chunk = b0 / Bc;
    const int* cnt = counts + chunk * 16;
    const int* lst = lists + (size_t)chunk * 16 * Bc;
    const int* smp = slotmap + (size_t)chunk * 16 * Bc;
    const int* wrk = work + chunk * gm1 * 16;
    const int* tot = totals + chunk;
    const int* ofs = offsets + chunk * 16;
    // compact routed x rows (streaming gather; latency hidden by TLP)
    gather_rows<<<dim3(Bc / 4, 16), 256, 0, stream>>>(xb, cnt, lst, ofs, xg, Bc, cap);
    // FC1 (sparse): h[offs[e]+slot][:] = relu(xg[offs[e]+slot] @ We1[e] + be1[e]); gn=8
    gemm_sparse<true><<<gm1 * 16 * 8, 256, 0, stream>>>(
        xg, 1024,
        We1t, 1024, (long long)1024 * 1024,
        h, 1024, be1, 1024, 1024,
        cnt, ofs, wrk, tot, 3, gm1, Bc, cap);
    // FC2 (sparse): eo[offs[e]+slot][:] = h[offs[e]+slot] @ We2[e] + be2[e]; gn=4
    // (eo aliases xg, dead after FC1)
    gemm_sparse<false><<<gm1 * 16 * 4, 256, 0, stream>>>(
        h, 1024,
        We2t, 1024, (long long)512 * 1024,
        eo, 512, be2, 512, 1024,
        cnt, ofs, wrk, tot, 2, gm1, Bc, cap);
    // combine into go rows [b0, b0+Bc) via offs + slotmap
    combine_kernel<<<dim3(Bc, 2), 128, 0, stream>>>(
        eo, g, go, b0, ofs, smp, Bc, cap);
  }

  // towers (full batch, dense + XCD swizzle)
  gemm_bt<true, true><<<64 * 4 * 2, 256, 0, stream>>>(
      go, 512, (long long)8192 * 512, Wh1t, 512, (long long)512 * 512,
      t1, 512, (long long)8192 * 512, bh1, 512, 512,
      64, 4);
  gemm_bt<true, false><<<64 * 2 * 2, 256, 0, stream>>>(
      t1, 512, (long long)8192 * 512, Wh2t, 512, (long long)256 * 512,
      t2, 256, (long long)8192 * 256, bh2, 256, 512,
      64, 2);

  final_dot<<<4096, 256, 0, stream>>>(t2, Wh3, bh3, (float*)d_out);
}